// Round 15
// baseline (405.035 us; speedup 1.0000x reference)
//
#include <hip/hip_runtime.h>

typedef unsigned short ushort_t;
typedef __attribute__((ext_vector_type(8))) short short8;
typedef __attribute__((ext_vector_type(4))) float f32x4;
typedef __attribute__((ext_vector_type(4))) unsigned short ush4;

#define MFMA_BF16(a, b, c) __builtin_amdgcn_mfma_f32_16x16x32_bf16((a), (b), (c), 0, 0, 0)

#define GLOAD_LDS16(GP, LP)                                                       \
  __builtin_amdgcn_global_load_lds(                                               \
      (const __attribute__((address_space(1))) void*)(GP),                        \
      (__attribute__((address_space(3))) void*)(LP), 16, 0, 0)

// anti-DCE liveness sinks (rule #17)
#define KEEP4(x) asm volatile("" ::"v"((x)[0]), "v"((x)[1]), "v"((x)[2]), "v"((x)[3]))
#define KEEPS8(x)                          \
  do {                                     \
    f32x4 _t = *(const f32x4*)&(x);        \
    KEEP4(_t);                             \
  } while (0)

#define T_LEN 1024
#define BATCH 4
#define NHEAD 16
#define DHEAD 64
#define EMB 1024

__device__ __forceinline__ ushort_t f2bf(float f) {
  unsigned u = __float_as_uint(f);
  u += 0x7fffu + ((u >> 16) & 1u);
  return (ushort_t)(u >> 16);
}

// ---------------- elementwise ----------------
__global__ void sample_w_kernel(const float* __restrict__ im, const float* __restrict__ ir,
                                const float* __restrict__ ie, ushort_t* __restrict__ io,
                                const float* __restrict__ pm, const float* __restrict__ pr,
                                const float* __restrict__ pe, ushort_t* __restrict__ po,
                                const float* __restrict__ om, const float* __restrict__ orh,
                                const float* __restrict__ oe, ushort_t* __restrict__ oo) {
  int i = blockIdx.x * 256 + threadIdx.x;
  const float *mu, *rho, *eps;
  ushort_t* out;
  int j;
  if (i < 786432) { mu = im; rho = ir; eps = ie; out = io; j = i; }
  else if (i < 1048576) { mu = pm; rho = pr; eps = pe; out = po; j = i - 786432; }
  else { mu = om; rho = orh; eps = oe; out = oo; j = i - 1048576; }
  f32x4 m = *(const f32x4*)(mu + (size_t)j * 4);
  f32x4 r = *(const f32x4*)(rho + (size_t)j * 4);
  f32x4 e = *(const f32x4*)(eps + (size_t)j * 4);
  ush4 o;
#pragma unroll
  for (int k = 0; k < 4; ++k) o[k] = f2bf(m[k] + log1pf(__expf(r[k])) * e[k]);
  *(ush4*)(out + (size_t)j * 4) = o;
}

__global__ void sample_bias_kernel(
    const float* __restrict__ am, const float* __restrict__ ar, const float* __restrict__ ae, float* __restrict__ ao,
    const float* __restrict__ bm, const float* __restrict__ br, const float* __restrict__ be, float* __restrict__ bo,
    const float* __restrict__ cm, const float* __restrict__ cr, const float* __restrict__ ce, float* __restrict__ co,
    const float* __restrict__ dm, const float* __restrict__ dr, const float* __restrict__ de, float* __restrict__ dof,
    const float* __restrict__ em, const float* __restrict__ er, const float* __restrict__ ee, float* __restrict__ eo) {
  int i = blockIdx.x * 256 + threadIdx.x;
  if (i < 3072) {
    ao[i] = am[i] + log1pf(__expf(ar[i])) * ae[i];
  } else if (i < 4096) {
    int j = i - 3072; bo[j] = bm[j] + log1pf(__expf(br[j])) * be[j];
  } else if (i < 5120) {
    int j = i - 4096; co[j] = cm[j] + log1pf(__expf(cr[j])) * ce[j];
  } else if (i < 6144) {
    int j = i - 5120; dof[j] = dm[j] + log1pf(__expf(dr[j])) * de[j];
  } else if (i < 7168) {
    int j = i - 6144; eo[j] = em[j] + log1pf(__expf(er[j])) * ee[j];
  }
}

__global__ void cast_bf16x4_kernel(const float* __restrict__ in, ushort_t* __restrict__ out, int n4) {
  int i = blockIdx.x * 256 + threadIdx.x;
  if (i < n4) {
    f32x4 v = *(const f32x4*)(in + (size_t)i * 4);
    ush4 o;
#pragma unroll
    for (int j = 0; j < 4; ++j) o[j] = f2bf(v[j]);
    *(ush4*)(out + (size_t)i * 4) = o;
  }
}

__global__ void zero_rhp_pad_kernel(ushort_t* __restrict__ rhp) {
  int idx = blockIdx.x * 256 + threadIdx.x;
  int dd = idx & 63;
  int pr = (idx >> 6) & 127;
  int h = idx >> 13;
  int phys = (pr < 64) ? pr : (pr - 64 + 1088);
  rhp[((size_t)h * 1152 + phys) * 64 + dd] = 0;
}

// ---------------- GEMM (out-proj) ----------------
__global__ __launch_bounds__(256, 2)
void gemm_bt_kernel(const ushort_t* __restrict__ A, const ushort_t* __restrict__ Bt,
                    const float* __restrict__ bias, float* __restrict__ C,
                    int M, int N, int K) {
  __shared__ ushort_t As[128 * 32];
  __shared__ ushort_t Bs[128 * 32];
  const int tid = threadIdx.x;
  const int w = tid >> 6, l = tid & 63;
  const int m0 = blockIdx.x * 128, n0 = blockIdx.y * 128;
  const int wr = w >> 1, wc = w & 1;
  const int fr = l & 15, fk = (l >> 4) * 8;

  f32x4 acc[4][4] = {};

  for (int k0 = 0; k0 < K; k0 += 32) {
    __syncthreads();
#pragma unroll
    for (int p = 0; p < 2; ++p) {
      int c = p * 256 + tid;
      int row = c >> 2, col = (c & 3) * 8;
      GLOAD_LDS16(&A[(size_t)(m0 + row) * K + k0 + col], &As[c * 8]);
      GLOAD_LDS16(&Bt[(size_t)(n0 + row) * K + k0 + col], &Bs[c * 8]);
    }
    __syncthreads();
    short8 af[4], bf[4];
#pragma unroll
    for (int mi = 0; mi < 4; ++mi) af[mi] = *(const short8*)(&As[(wr * 64 + mi * 16 + fr) * 32 + fk]);
#pragma unroll
    for (int ni = 0; ni < 4; ++ni) bf[ni] = *(const short8*)(&Bs[(wc * 64 + ni * 16 + fr) * 32 + fk]);
#pragma unroll
    for (int mi = 0; mi < 4; ++mi)
#pragma unroll
      for (int ni = 0; ni < 4; ++ni)
        acc[mi][ni] = MFMA_BF16(af[mi], bf[ni], acc[mi][ni]);
  }

#pragma unroll
  for (int ni = 0; ni < 4; ++ni) {
    int col = n0 + wc * 64 + ni * 16 + fr;
    float bv = bias[col];
#pragma unroll
    for (int mi = 0; mi < 4; ++mi) {
#pragma unroll
      for (int q = 0; q < 4; ++q) {
        int row = m0 + wr * 64 + mi * 16 + (l >> 4) * 4 + q;
        C[(size_t)row * N + col] = acc[mi][ni][q] + bv;
      }
    }
  }
}

// ---------------- merged QKV + pos GEMM ----------------
__global__ __launch_bounds__(256, 2)
void gemm_qkvpos_kernel(const ushort_t* __restrict__ x_bf, const ushort_t* __restrict__ in_w_bf,
                        const float* __restrict__ in_b,
                        const float* __restrict__ rwb, const float* __restrict__ rrb,
                        const ushort_t* __restrict__ posx_bf, const ushort_t* __restrict__ pos_w_bf,
                        const float* __restrict__ pos_b,
                        ushort_t* __restrict__ qrw, ushort_t* __restrict__ qrr,
                        ushort_t* __restrict__ kbuf, ushort_t* __restrict__ vt,
                        ushort_t* __restrict__ rhp) {
  __shared__ ushort_t As[128 * 32];
  __shared__ ushort_t Bs[128 * 32];
  const int K = 1024;
  const int tid = threadIdx.x;
  const int w = tid >> 6, l = tid & 63;
  const int bid = blockIdx.x;
  const bool isPos = bid >= 768;
  int m0, n0;
  const ushort_t *A, *Bt;
  if (!isPos) {
    m0 = (bid & 31) * 128; n0 = (bid >> 5) * 128; A = x_bf; Bt = in_w_bf;
  } else {
    int pb2 = bid - 768;
    m0 = (pb2 & 7) * 128; n0 = (pb2 >> 3) * 128; A = posx_bf; Bt = pos_w_bf;
  }
  const int wr = w >> 1, wc = w & 1;
  const int fr = l & 15, fk = (l >> 4) * 8;

  f32x4 acc[4][4] = {};

  for (int k0 = 0; k0 < K; k0 += 32) {
    __syncthreads();
#pragma unroll
    for (int p = 0; p < 2; ++p) {
      int c = p * 256 + tid;
      int row = c >> 2, col = (c & 3) * 8;
      GLOAD_LDS16(&A[(size_t)(m0 + row) * K + k0 + col], &As[c * 8]);
      GLOAD_LDS16(&Bt[(size_t)(n0 + row) * K + k0 + col], &Bs[c * 8]);
    }
    __syncthreads();
    short8 af[4], bf[4];
#pragma unroll
    for (int mi = 0; mi < 4; ++mi) af[mi] = *(const short8*)(&As[(wr * 64 + mi * 16 + fr) * 32 + fk]);
#pragma unroll
    for (int ni = 0; ni < 4; ++ni) bf[ni] = *(const short8*)(&Bs[(wc * 64 + ni * 16 + fr) * 32 + fk]);
#pragma unroll
    for (int mi = 0; mi < 4; ++mi)
#pragma unroll
      for (int ni = 0; ni < 4; ++ni)
        acc[mi][ni] = MFMA_BF16(af[mi], bf[ni], acc[mi][ni]);
  }

  if (!isPos) {
#pragma unroll
    for (int ni = 0; ni < 4; ++ni) {
      int col = n0 + wc * 64 + ni * 16 + fr;
      int part = col >> 10;
      int e = col & 1023;
      int hh = e >> 6, dd = e & 63;
      float bv = in_b[col];
      float rwv = rwb[e];
      float rrv = rrb[e];
#pragma unroll
      for (int mi = 0; mi < 4; ++mi) {
#pragma unroll
        for (int q = 0; q < 4; ++q) {
          int row = m0 + wr * 64 + mi * 16 + (l >> 4) * 4 + q;
          int t = row >> 2, b = row & 3;
          float v = acc[mi][ni][q] + bv;
          if (part == 0) {
            unsigned idx = (((unsigned)(b * 16 + hh) * 1024 + t) << 6) + dd;
            qrw[idx] = f2bf(v + rwv);
            qrr[idx] = f2bf(v + rrv);
          } else if (part == 1) {
            unsigned idx = (((unsigned)(b * 16 + hh) * 1024 + t) << 6) + dd;
            kbuf[idx] = f2bf(v);
          } else {
            vt[(((unsigned)(b * 16 + hh) * 64 + dd) << 10) + t] = f2bf(v);
          }
        }
      }
    }
  } else {
#pragma unroll
    for (int ni = 0; ni < 4; ++ni) {
      int col = n0 + wc * 64 + ni * 16 + fr;
      int hh = col >> 6, dd = col & 63;
      float bv = pos_b[col];
#pragma unroll
      for (int mi = 0; mi < 4; ++mi) {
#pragma unroll
        for (int q = 0; q < 4; ++q) {
          int t = m0 + wr * 64 + mi * 16 + (l >> 4) * 4 + q;
          rhp[((unsigned)hh * 1152 + 64 + t) * 64 + dd] = f2bf(acc[mi][ni][q] + bv);
        }
      }
    }
  }
}

// ---------------- attn v7 with phase-ablation template (diagnostic round) ----------------
// VAR=0 full; VAR=3 stub score-operands (rf loads + kf reads + QK/BD MFMA);
// VAR=1 stub softmax-gather (bpermutes + exp + P-LDS roundtrip);
// VAR=2 stub PV (vf reads + PV MFMA). Stubs keep upstream live via asm sinks.
template <int VAR>
__global__ __launch_bounds__(256, 2)
void attn_kernel(const ushort_t* __restrict__ qrw, const ushort_t* __restrict__ qrr,
                 const ushort_t* __restrict__ kb, const ushort_t* __restrict__ vt,
                 const ushort_t* __restrict__ rhp, ushort_t* __restrict__ ctx) {
  __shared__ __attribute__((aligned(16))) ushort_t KV[2][8192];
  __shared__ __attribute__((aligned(16))) char PtB[4][2048];

  const int tid = threadIdx.x, w = tid >> 6, l = tid & 63;
  const int bid = blockIdx.x;
  const int g = bid & 63;
  const int h = ((g & 7) << 1) | ((g >> 3) & 1);
  const int b = g >> 4;
  const int bh = b * 16 + h;
  const int p = bid >> 6;
  const int istA = (15 - p) * 64 + w * 16;
  const int istB = p * 64 + w * 16;
  const int njt = 16 - p;
  const int njtB = p + 1;
  const int fr = l & 15, fkq = (l >> 4) * 8;
  const float scale = 0.125f;
  char* Pw = PtB[w];

  short8 aqwA0, aqwA1, aqrA0, aqrA1, aqwB0, aqwB1, aqrB0, aqrB1;
  {
    unsigned qa = ((unsigned)bh * T_LEN + istA + fr) * 64 + fkq;
    aqwA0 = *(const short8*)(qrw + qa);
    aqwA1 = *(const short8*)(qrw + qa + 32);
    aqrA0 = *(const short8*)(qrr + qa);
    aqrA1 = *(const short8*)(qrr + qa + 32);
    unsigned qb = ((unsigned)bh * T_LEN + istB + fr) * 64 + fkq;
    aqwB0 = *(const short8*)(qrw + qb);
    aqwB1 = *(const short8*)(qrw + qb + 32);
    aqrB0 = *(const short8*)(qrr + qb);
    aqrB1 = *(const short8*)(qrr + qb + 32);
  }

  const int srow = 16 * w + (l >> 3);
  const unsigned sswz = (unsigned)(((l & 7) ^ (l >> 3)) << 4);
  const unsigned kgcol = (unsigned)(l & 7) * 8;
  const unsigned swzr = (unsigned)(fr & 7) << 4;

  const unsigned rbaseA = ((unsigned)h * 1152 + 64 + 1008 - istA + fr) * 64 + fkq;
  const unsigned rbaseB = ((unsigned)h * 1152 + 64 + 1008 - istB + fr) * 64 + fkq;

  float sA[4] = {0.f, 0.f, 0.f, 0.f}, sB[4] = {0.f, 0.f, 0.f, 0.f};
  f32x4 oA[4] = {}, oB[4] = {};

  short8 sg0, sg1, sg2, sg3;
#define STAGE_LOAD(J0)                                                              \
  do {                                                                              \
    sg0 = *(const short8*)(kb + ((unsigned)bh * 1024 + (unsigned)(J0) + srow) * 64 + kgcol);      \
    sg1 = *(const short8*)(kb + ((unsigned)bh * 1024 + (unsigned)(J0) + srow + 8) * 64 + kgcol);  \
    sg2 = *(const short8*)(vt + ((unsigned)bh * 64 + srow) * 1024 + (unsigned)(J0) + kgcol);      \
    sg3 = *(const short8*)(vt + ((unsigned)bh * 64 + srow + 8) * 1024 + (unsigned)(J0) + kgcol);  \
  } while (0)
#define STAGE_WRITE(BUF)                                                            \
  do {                                                                              \
    char* KS_ = (char*)KV[BUF];                                                     \
    *(short8*)(KS_ + (unsigned)srow * 128 + sswz) = sg0;                            \
    *(short8*)(KS_ + (unsigned)(srow + 8) * 128 + sswz) = sg1;                      \
    *(short8*)(KS_ + 8192 + (unsigned)srow * 128 + sswz) = sg2;                     \
    *(short8*)(KS_ + 8192 + (unsigned)(srow + 8) * 128 + sswz) = sg3;               \
  } while (0)

#define STRIP_TILE(AQW0, AQW1, AQR0, AQR1, RBASE, IST, SRUN, OACC)                   \
  do {                                                                               \
    f32x4 ac[4];                                                                     \
    f32x4 pb[5];                                                                     \
    if constexpr (VAR != 3) {                                                        \
      short8 rf[10];                                                                 \
      unsigned roff = (RBASE) + (unsigned)j0 * 64;                                   \
      _Pragma("unroll")                                                              \
      for (int f = 0; f < 5; ++f) {                                                  \
        rf[2 * f] = *(const short8*)(rhp + roff + f * 1024);                         \
        rf[2 * f + 1] = *(const short8*)(rhp + roff + f * 1024 + 32);                \
      }                                                                              \
      short8 kf[8];                                                                  \
      _Pragma("unroll")                                                              \
      for (int f = 0; f < 4; ++f) {                                                  \
        unsigned rowb = (unsigned)(f * 16 + fr) * 128;                               \
        kf[2 * f] = *(const short8*)(KS + rowb + (((unsigned)fkq * 2) ^ swzr));      \
        kf[2 * f + 1] = *(const short8*)(KS + rowb + (((unsigned)fkq * 2 + 64) ^ swzr)); \
      }                                                                              \
      _Pragma("unroll")                                                              \
      for (int f = 0; f < 4; ++f) ac[f] = (f32x4){0.f, 0.f, 0.f, 0.f};               \
      _Pragma("unroll")                                                              \
      for (int f = 0; f < 5; ++f) pb[f] = (f32x4){0.f, 0.f, 0.f, 0.f};               \
      __builtin_amdgcn_s_setprio(1);                                                 \
      _Pragma("unroll")                                                              \
      for (int f = 0; f < 4; ++f) {                                                  \
        ac[f] = MFMA_BF16(AQW0, kf[2 * f], ac[f]);                                   \
        ac[f] = MFMA_BF16(AQW1, kf[2 * f + 1], ac[f]);                               \
      }                                                                              \
      _Pragma("unroll")                                                              \
      for (int f = 0; f < 5; ++f) {                                                  \
        pb[f] = MFMA_BF16(AQR0, rf[2 * f], pb[f]);                                   \
        pb[f] = MFMA_BF16(AQR1, rf[2 * f + 1], pb[f]);                               \
      }                                                                              \
      __builtin_amdgcn_s_setprio(0);                                                 \
    } else {                                                                         \
      f32x4 jnk = *(const f32x4*)&(AQW0);                                            \
      _Pragma("unroll")                                                              \
      for (int f = 0; f < 4; ++f) ac[f] = jnk;                                       \
      _Pragma("unroll")                                                              \
      for (int f = 0; f < 5; ++f) pb[f] = jnk;                                       \
    }                                                                                \
    short8 pa0, pa1;                                                                 \
    if constexpr (VAR != 1) {                                                        \
      _Pragma("unroll")                                                              \
      for (int q = 0; q < 4; ++q) {                                                  \
        int ri = 4 * (l >> 4) + q;                                                   \
        int e = 15 + fr - ri;                                                        \
        int src = (l & 48) | (e & 15);                                               \
        float sh[5];                                                                 \
        _Pragma("unroll")                                                            \
        for (int f = 0; f < 5; ++f) sh[f] = __shfl(pb[f][q], src, 64);               \
        int hi = e >> 4;                                                             \
        int ig = (IST) + ri;                                                         \
        _Pragma("unroll")                                                            \
        for (int ni = 0; ni < 4; ++ni) {                                             \
          float pv = hi ? sh[ni + 1] : sh[ni];                                       \
          float s = (ac[ni][q] + pv) * scale - 20.0f;                                \
          int jg = j0 + ni * 16 + fr;                                                \
          float pp = (jg > ig) ? 0.f : __expf(s);                                    \
          *(ushort_t*)(Pw + (((ri * 128) + (ni * 16 + fr) * 2) ^ ((ri & 7) << 4))) = f2bf(pp); \
          SRUN[q] += pp;                                                             \
        }                                                                            \
      }                                                                              \
      pa0 = *(const short8*)(Pw + ((fr * 128 + fkq * 2) ^ ((fr & 7) << 4)));         \
      pa1 = *(const short8*)(Pw + ((fr * 128 + 64 + fkq * 2) ^ ((fr & 7) << 4)));    \
    } else {                                                                         \
      _Pragma("unroll")                                                              \
      for (int f = 0; f < 4; ++f) KEEP4(ac[f]);                                      \
      _Pragma("unroll")                                                              \
      for (int f = 0; f < 5; ++f) KEEP4(pb[f]);                                      \
      _Pragma("unroll")                                                              \
      for (int q = 0; q < 4; ++q) SRUN[q] += 1.0f;                                   \
      pa0 = (AQW0);                                                                  \
      pa1 = (AQW1);                                                                  \
    }                                                                                \
    if constexpr (VAR != 2) {                                                        \
      short8 vf[8];                                                                  \
      _Pragma("unroll")                                                              \
      for (int dg = 0; dg < 4; ++dg) {                                               \
        unsigned rowb = 8192 + (unsigned)(dg * 16 + fr) * 128;                       \
        vf[2 * dg] = *(const short8*)(KS + rowb + (((unsigned)fkq * 2) ^ swzr));     \
        vf[2 * dg + 1] = *(const short8*)(KS + rowb + (((unsigned)(64 + fkq * 2)) ^ swzr)); \
      }                                                                              \
      __builtin_amdgcn_s_setprio(1);                                                 \
      _Pragma("unroll")                                                              \
      for (int dg = 0; dg < 4; ++dg) {                                               \
        OACC[dg] = MFMA_BF16(pa0, vf[2 * dg], OACC[dg]);                             \
        OACC[dg] = MFMA_BF16(pa1, vf[2 * dg + 1], OACC[dg]);                         \
      }                                                                              \
      __builtin_amdgcn_s_setprio(0);                                                 \
    } else {                                                                         \
      KEEPS8(pa0);                                                                   \
      KEEPS8(pa1);                                                                   \
    }                                                                                \
  } while (0)

  STAGE_LOAD(0);
  STAGE_WRITE(0);
  __syncthreads();

  for (int jt = 0; jt < njt; ++jt) {
    const int j0 = jt << 6;
    const char* KS = (const char*)KV[jt & 1];

    if (jt + 1 < njt) STAGE_LOAD((jt + 1) << 6);

    STRIP_TILE(aqwA0, aqwA1, aqrA0, aqrA1, rbaseA, istA, sA, oA);
    if (jt < njtB) STRIP_TILE(aqwB0, aqwB1, aqrB0, aqrB1, rbaseB, istB, sB, oB);

    if (jt + 1 < njt) STAGE_WRITE((jt + 1) & 1);
    __syncthreads();
  }

#pragma unroll
  for (int q = 0; q < 4; ++q) {
    float a = sA[q], bq = sB[q];
#pragma unroll
    for (int o2 = 8; o2; o2 >>= 1) {
      a += __shfl_xor(a, o2, 64);
      bq += __shfl_xor(bq, o2, 64);
    }
    sA[q] = a;
    sB[q] = bq;
  }
#pragma unroll
  for (int dg = 0; dg < 4; ++dg) {
#pragma unroll
    for (int q = 0; q < 4; ++q) {
      int dd = dg * 16 + fr;
      int igA = istA + 4 * (l >> 4) + q;
      ctx[((size_t)igA * BATCH + b) * EMB + h * 64 + dd] = f2bf(oA[dg][q] / sA[q]);
      int igB = istB + 4 * (l >> 4) + q;
      ctx[((size_t)igB * BATCH + b) * EMB + h * 64 + dd] = f2bf(oB[dg][q] / sB[q]);
    }
  }
}

// ---------------- launch ----------------
extern "C" void kernel_launch(void* const* d_in, const int* in_sizes, int n_in,
                              void* d_out, int out_size, void* d_ws, size_t ws_size,
                              hipStream_t stream) {
  (void)in_sizes; (void)n_in; (void)out_size; (void)ws_size;
  const float* x = (const float*)d_in[0];
  const float* pos = (const float*)d_in[1];
  const float* in_w_mu = (const float*)d_in[3];
  const float* in_w_rho = (const float*)d_in[4];
  const float* in_w_eps = (const float*)d_in[5];
  const float* in_b_mu = (const float*)d_in[6];
  const float* in_b_rho = (const float*)d_in[7];
  const float* in_b_eps = (const float*)d_in[8];
  const float* pos_w_mu = (const float*)d_in[9];
  const float* pos_w_rho = (const float*)d_in[10];
  const float* pos_w_eps = (const float*)d_in[11];
  const float* pos_b_mu = (const float*)d_in[12];
  const float* pos_b_rho = (const float*)d_in[13];
  const float* pos_b_eps = (const float*)d_in[14];
  const float* out_w_mu = (const float*)d_in[15];
  const float* out_w_rho = (const float*)d_in[16];
  const float* out_w_eps = (const float*)d_in[17];
  const float* out_b_mu = (const float*)d_in[18];
  const float* out_b_rho = (const float*)d_in[19];
  const float* out_b_eps = (const float*)d_in[20];
  const float* rw_mu = (const float*)d_in[21];
  const float* rw_rho = (const float*)d_in[22];
  const float* rw_eps = (const float*)d_in[23];
  const float* rr_mu = (const float*)d_in[24];
  const float* rr_rho = (const float*)d_in[25];
  const float* rr_eps = (const float*)d_in[26];

  char* ws = (char*)d_ws;
  ushort_t* in_w_bf  = (ushort_t*)(ws + 0);
  ushort_t* pos_w_bf = (ushort_t*)(ws + 6291456);
  ushort_t* out_w_bf = (ushort_t*)(ws + 8388608);
  float* in_b  = (float*)(ws + 10485760);
  float* pos_b = (float*)(ws + 10498048);
  float* out_b = (float*)(ws + 10502144);
  float* rwb   = (float*)(ws + 10506240);
  float* rrb   = (float*)(ws + 10510336);
  ushort_t* x_bf    = (ushort_t*)(ws + 10514432);
  ushort_t* posx_bf = (ushort_t*)(ws + 18903040);
  ushort_t* qrw = (ushort_t*)(ws + 21000192);
  ushort_t* qrr = (ushort_t*)(ws + 29388800);
  ushort_t* kb  = (ushort_t*)(ws + 37777408);
  ushort_t* vt  = (ushort_t*)(ws + 46166016);
  ushort_t* rhp = (ushort_t*)(ws + 54554624);
  ushort_t* ctx = (ushort_t*)(ws + 56913920);        // [T][B][E] bf16
  ushort_t* ctx2 = (ushort_t*)(ws + 65302528);       // ablation scratch

  sample_w_kernel<<<5120, 256, 0, stream>>>(in_w_mu, in_w_rho, in_w_eps, in_w_bf,
                                            pos_w_mu, pos_w_rho, pos_w_eps, pos_w_bf,
                                            out_w_mu, out_w_rho, out_w_eps, out_w_bf);
  sample_bias_kernel<<<28, 256, 0, stream>>>(in_b_mu, in_b_rho, in_b_eps, in_b,
                                             pos_b_mu, pos_b_rho, pos_b_eps, pos_b,
                                             out_b_mu, out_b_rho, out_b_eps, out_b,
                                             rw_mu, rw_rho, rw_eps, rwb,
                                             rr_mu, rr_rho, rr_eps, rrb);
  cast_bf16x4_kernel<<<4096, 256, 0, stream>>>(x, x_bf, 1048576);
  cast_bf16x4_kernel<<<1024, 256, 0, stream>>>(pos, posx_bf, 262144);
  zero_rhp_pad_kernel<<<512, 256, 0, stream>>>(rhp);

  gemm_qkvpos_kernel<<<832, 256, 0, stream>>>(x_bf, in_w_bf, in_b, rwb, rrb,
                                              posx_bf, pos_w_bf, pos_b,
                                              qrw, qrr, kb, vt, rhp);

  // ---- ablation dispatches (diagnostic; results discarded) ----
  attn_kernel<3><<<dim3(512), 256, 0, stream>>>(qrw, qrr, kb, vt, rhp, ctx2);
  attn_kernel<1><<<dim3(512), 256, 0, stream>>>(qrw, qrr, kb, vt, rhp, ctx2);
  attn_kernel<2><<<dim3(512), 256, 0, stream>>>(qrw, qrr, kb, vt, rhp, ctx2);
  // ---- real attention ----
  attn_kernel<0><<<dim3(512), 256, 0, stream>>>(qrw, qrr, kb, vt, rhp, ctx);

  gemm_bt_kernel<<<dim3(32, 8), 256, 0, stream>>>(ctx, out_w_bf, out_b, (float*)d_out, 4096, 1024, 1024);
}

// Round 16
// 363.888 us; speedup vs baseline: 1.1131x; 1.1131x over previous
//
#include <hip/hip_runtime.h>

typedef unsigned short ushort_t;
typedef __attribute__((ext_vector_type(8))) short short8;
typedef __attribute__((ext_vector_type(4))) float f32x4;
typedef __attribute__((ext_vector_type(4))) unsigned short ush4;

#define MFMA_BF16(a, b, c) __builtin_amdgcn_mfma_f32_16x16x32_bf16((a), (b), (c), 0, 0, 0)

#define GLOAD_LDS16(GP, LP)                                                       \
  __builtin_amdgcn_global_load_lds(                                               \
      (const __attribute__((address_space(1))) void*)(GP),                        \
      (__attribute__((address_space(3))) void*)(LP), 16, 0, 0)

#define T_LEN 1024
#define BATCH 4
#define NHEAD 16
#define DHEAD 64
#define EMB 1024

__device__ __forceinline__ ushort_t f2bf(float f) {
  unsigned u = __float_as_uint(f);
  u += 0x7fffu + ((u >> 16) & 1u);
  return (ushort_t)(u >> 16);
}

// ---------------- elementwise ----------------
__global__ void sample_w_kernel(const float* __restrict__ im, const float* __restrict__ ir,
                                const float* __restrict__ ie, ushort_t* __restrict__ io,
                                const float* __restrict__ pm, const float* __restrict__ pr,
                                const float* __restrict__ pe, ushort_t* __restrict__ po,
                                const float* __restrict__ om, const float* __restrict__ orh,
                                const float* __restrict__ oe, ushort_t* __restrict__ oo) {
  int i = blockIdx.x * 256 + threadIdx.x;
  const float *mu, *rho, *eps;
  ushort_t* out;
  int j;
  if (i < 786432) { mu = im; rho = ir; eps = ie; out = io; j = i; }
  else if (i < 1048576) { mu = pm; rho = pr; eps = pe; out = po; j = i - 786432; }
  else { mu = om; rho = orh; eps = oe; out = oo; j = i - 1048576; }
  f32x4 m = *(const f32x4*)(mu + (size_t)j * 4);
  f32x4 r = *(const f32x4*)(rho + (size_t)j * 4);
  f32x4 e = *(const f32x4*)(eps + (size_t)j * 4);
  ush4 o;
#pragma unroll
  for (int k = 0; k < 4; ++k) o[k] = f2bf(m[k] + log1pf(__expf(r[k])) * e[k]);
  *(ush4*)(out + (size_t)j * 4) = o;
}

__global__ void sample_bias_kernel(
    const float* __restrict__ am, const float* __restrict__ ar, const float* __restrict__ ae, float* __restrict__ ao,
    const float* __restrict__ bm, const float* __restrict__ br, const float* __restrict__ be, float* __restrict__ bo,
    const float* __restrict__ cm, const float* __restrict__ cr, const float* __restrict__ ce, float* __restrict__ co,
    const float* __restrict__ dm, const float* __restrict__ dr, const float* __restrict__ de, float* __restrict__ dof,
    const float* __restrict__ em, const float* __restrict__ er, const float* __restrict__ ee, float* __restrict__ eo) {
  int i = blockIdx.x * 256 + threadIdx.x;
  if (i < 3072) {
    ao[i] = am[i] + log1pf(__expf(ar[i])) * ae[i];
  } else if (i < 4096) {
    int j = i - 3072; bo[j] = bm[j] + log1pf(__expf(br[j])) * be[j];
  } else if (i < 5120) {
    int j = i - 4096; co[j] = cm[j] + log1pf(__expf(cr[j])) * ce[j];
  } else if (i < 6144) {
    int j = i - 5120; dof[j] = dm[j] + log1pf(__expf(dr[j])) * de[j];
  } else if (i < 7168) {
    int j = i - 6144; eo[j] = em[j] + log1pf(__expf(er[j])) * ee[j];
  }
}

__global__ void cast_bf16x4_kernel(const float* __restrict__ in, ushort_t* __restrict__ out, int n4) {
  int i = blockIdx.x * 256 + threadIdx.x;
  if (i < n4) {
    f32x4 v = *(const f32x4*)(in + (size_t)i * 4);
    ush4 o;
#pragma unroll
    for (int j = 0; j < 4; ++j) o[j] = f2bf(v[j]);
    *(ush4*)(out + (size_t)i * 4) = o;
  }
}

__global__ void zero_rhp_pad_kernel(ushort_t* __restrict__ rhp) {
  int idx = blockIdx.x * 256 + threadIdx.x;
  int dd = idx & 63;
  int pr = (idx >> 6) & 127;
  int h = idx >> 13;
  int phys = (pr < 64) ? pr : (pr - 64 + 1088);
  rhp[((size_t)h * 1152 + phys) * 64 + dd] = 0;
}

// ---------------- GEMM (out-proj) ----------------
__global__ __launch_bounds__(256, 2)
void gemm_bt_kernel(const ushort_t* __restrict__ A, const ushort_t* __restrict__ Bt,
                    const float* __restrict__ bias, float* __restrict__ C,
                    int M, int N, int K) {
  __shared__ ushort_t As[128 * 32];
  __shared__ ushort_t Bs[128 * 32];
  const int tid = threadIdx.x;
  const int w = tid >> 6, l = tid & 63;
  const int m0 = blockIdx.x * 128, n0 = blockIdx.y * 128;
  const int wr = w >> 1, wc = w & 1;
  const int fr = l & 15, fk = (l >> 4) * 8;

  f32x4 acc[4][4] = {};

  for (int k0 = 0; k0 < K; k0 += 32) {
    __syncthreads();
#pragma unroll
    for (int p = 0; p < 2; ++p) {
      int c = p * 256 + tid;
      int row = c >> 2, col = (c & 3) * 8;
      GLOAD_LDS16(&A[(size_t)(m0 + row) * K + k0 + col], &As[c * 8]);
      GLOAD_LDS16(&Bt[(size_t)(n0 + row) * K + k0 + col], &Bs[c * 8]);
    }
    __syncthreads();
    short8 af[4], bf[4];
#pragma unroll
    for (int mi = 0; mi < 4; ++mi) af[mi] = *(const short8*)(&As[(wr * 64 + mi * 16 + fr) * 32 + fk]);
#pragma unroll
    for (int ni = 0; ni < 4; ++ni) bf[ni] = *(const short8*)(&Bs[(wc * 64 + ni * 16 + fr) * 32 + fk]);
#pragma unroll
    for (int mi = 0; mi < 4; ++mi)
#pragma unroll
      for (int ni = 0; ni < 4; ++ni)
        acc[mi][ni] = MFMA_BF16(af[mi], bf[ni], acc[mi][ni]);
  }

#pragma unroll
  for (int ni = 0; ni < 4; ++ni) {
    int col = n0 + wc * 64 + ni * 16 + fr;
    float bv = bias[col];
#pragma unroll
    for (int mi = 0; mi < 4; ++mi) {
#pragma unroll
      for (int q = 0; q < 4; ++q) {
        int row = m0 + wr * 64 + mi * 16 + (l >> 4) * 4 + q;
        C[(size_t)row * N + col] = acc[mi][ni][q] + bv;
      }
    }
  }
}

// ---------------- merged QKV + pos GEMM ----------------
__global__ __launch_bounds__(256, 2)
void gemm_qkvpos_kernel(const ushort_t* __restrict__ x_bf, const ushort_t* __restrict__ in_w_bf,
                        const float* __restrict__ in_b,
                        const float* __restrict__ rwb, const float* __restrict__ rrb,
                        const ushort_t* __restrict__ posx_bf, const ushort_t* __restrict__ pos_w_bf,
                        const float* __restrict__ pos_b,
                        ushort_t* __restrict__ qrw, ushort_t* __restrict__ qrr,
                        ushort_t* __restrict__ kbuf, ushort_t* __restrict__ vt,
                        ushort_t* __restrict__ rhp) {
  __shared__ ushort_t As[128 * 32];
  __shared__ ushort_t Bs[128 * 32];
  const int K = 1024;
  const int tid = threadIdx.x;
  const int w = tid >> 6, l = tid & 63;
  const int bid = blockIdx.x;
  const bool isPos = bid >= 768;
  int m0, n0;
  const ushort_t *A, *Bt;
  if (!isPos) {
    m0 = (bid & 31) * 128; n0 = (bid >> 5) * 128; A = x_bf; Bt = in_w_bf;
  } else {
    int pb2 = bid - 768;
    m0 = (pb2 & 7) * 128; n0 = (pb2 >> 3) * 128; A = posx_bf; Bt = pos_w_bf;
  }
  const int wr = w >> 1, wc = w & 1;
  const int fr = l & 15, fk = (l >> 4) * 8;

  f32x4 acc[4][4] = {};

  for (int k0 = 0; k0 < K; k0 += 32) {
    __syncthreads();
#pragma unroll
    for (int p = 0; p < 2; ++p) {
      int c = p * 256 + tid;
      int row = c >> 2, col = (c & 3) * 8;
      GLOAD_LDS16(&A[(size_t)(m0 + row) * K + k0 + col], &As[c * 8]);
      GLOAD_LDS16(&Bt[(size_t)(n0 + row) * K + k0 + col], &Bs[c * 8]);
    }
    __syncthreads();
    short8 af[4], bf[4];
#pragma unroll
    for (int mi = 0; mi < 4; ++mi) af[mi] = *(const short8*)(&As[(wr * 64 + mi * 16 + fr) * 32 + fk]);
#pragma unroll
    for (int ni = 0; ni < 4; ++ni) bf[ni] = *(const short8*)(&Bs[(wc * 64 + ni * 16 + fr) * 32 + fk]);
#pragma unroll
    for (int mi = 0; mi < 4; ++mi)
#pragma unroll
      for (int ni = 0; ni < 4; ++ni)
        acc[mi][ni] = MFMA_BF16(af[mi], bf[ni], acc[mi][ni]);
  }

  if (!isPos) {
#pragma unroll
    for (int ni = 0; ni < 4; ++ni) {
      int col = n0 + wc * 64 + ni * 16 + fr;
      int part = col >> 10;
      int e = col & 1023;
      int hh = e >> 6, dd = e & 63;
      float bv = in_b[col];
      float rwv = rwb[e];
      float rrv = rrb[e];
#pragma unroll
      for (int mi = 0; mi < 4; ++mi) {
#pragma unroll
        for (int q = 0; q < 4; ++q) {
          int row = m0 + wr * 64 + mi * 16 + (l >> 4) * 4 + q;
          int t = row >> 2, b = row & 3;
          float v = acc[mi][ni][q] + bv;
          if (part == 0) {
            unsigned idx = (((unsigned)(b * 16 + hh) * 1024 + t) << 6) + dd;
            qrw[idx] = f2bf(v + rwv);
            qrr[idx] = f2bf(v + rrv);
          } else if (part == 1) {
            unsigned idx = (((unsigned)(b * 16 + hh) * 1024 + t) << 6) + dd;
            kbuf[idx] = f2bf(v);
          } else {
            vt[(((unsigned)(b * 16 + hh) * 64 + dd) << 10) + t] = f2bf(v);
          }
        }
      }
    }
  } else {
#pragma unroll
    for (int ni = 0; ni < 4; ++ni) {
      int col = n0 + wc * 64 + ni * 16 + fr;
      int hh = col >> 6, dd = col & 63;
      float bv = pos_b[col];
#pragma unroll
      for (int mi = 0; mi < 4; ++mi) {
#pragma unroll
        for (int q = 0; q < 4; ++q) {
          int t = m0 + wr * 64 + mi * 16 + (l >> 4) * 4 + q;
          rhp[((unsigned)hh * 1152 + 64 + t) * 64 + dd] = f2bf(acc[mi][ni][q] + bv);
        }
      }
    }
  }
}

// ---------------- attn v8: dual-strip with independent phase chains ----------------
// R15 ablation: the 3 phases (score / gather-softmax / PV) serialize (~40us each of 109).
// v8 breaks the strip-A/strip-B WAR hazard (separate P buffers) and orders the dual-tile
// body so chain B's phases slot into chain A's latency gaps. vf shared between strips.
__global__ __launch_bounds__(256, 2)
void attn_kernel(const ushort_t* __restrict__ qrw, const ushort_t* __restrict__ qrr,
                 const ushort_t* __restrict__ kb, const ushort_t* __restrict__ vt,
                 const ushort_t* __restrict__ rhp, ushort_t* __restrict__ ctx) {
  __shared__ __attribute__((aligned(16))) ushort_t KV[2][8192];  // 32KB: [buf][K 8KB | V 8KB]
  __shared__ __attribute__((aligned(16))) char PtA[4][2048];     // strip-A P transpose
  __shared__ __attribute__((aligned(16))) char PtBB[4][2048];    // strip-B P transpose

  const int tid = threadIdx.x, w = tid >> 6, l = tid & 63;
  const int bid = blockIdx.x;
  const int g = bid & 63;
  const int h = ((g & 7) << 1) | ((g >> 3) & 1);   // bid%8 fixes the head-pair (XCD L2 locality)
  const int b = g >> 4;
  const int bh = b * 16 + h;
  const int p = bid >> 6;                          // pair index 0..7
  const int istA = (15 - p) * 64 + w * 16;
  const int istB = p * 64 + w * 16;
  const int njt = 16 - p;
  const int njtB = p + 1;
  const int fr = l & 15, fkq = (l >> 4) * 8;
  const float scale = 0.125f;
  char* PwA = PtA[w];
  char* PwB = PtBB[w];

  short8 aqwA0, aqwA1, aqrA0, aqrA1, aqwB0, aqwB1, aqrB0, aqrB1;
  {
    unsigned qa = ((unsigned)bh * T_LEN + istA + fr) * 64 + fkq;
    aqwA0 = *(const short8*)(qrw + qa);
    aqwA1 = *(const short8*)(qrw + qa + 32);
    aqrA0 = *(const short8*)(qrr + qa);
    aqrA1 = *(const short8*)(qrr + qa + 32);
    unsigned qb = ((unsigned)bh * T_LEN + istB + fr) * 64 + fkq;
    aqwB0 = *(const short8*)(qrw + qb);
    aqwB1 = *(const short8*)(qrw + qb + 32);
    aqrB0 = *(const short8*)(qrr + qb);
    aqrB1 = *(const short8*)(qrr + qb + 32);
  }

  const int srow = 16 * w + (l >> 3);
  const unsigned sswz = (unsigned)(((l & 7) ^ (l >> 3)) << 4);
  const unsigned kgcol = (unsigned)(l & 7) * 8;
  const unsigned swzr = (unsigned)(fr & 7) << 4;

  const unsigned rbaseA = ((unsigned)h * 1152 + 64 + 1008 - istA + fr) * 64 + fkq;
  const unsigned rbaseB = ((unsigned)h * 1152 + 64 + 1008 - istB + fr) * 64 + fkq;

  float sA[4] = {0.f, 0.f, 0.f, 0.f}, sB[4] = {0.f, 0.f, 0.f, 0.f};
  f32x4 oA[4] = {}, oB[4] = {};

  short8 sg0, sg1, sg2, sg3;
#define STAGE_LOAD(J0)                                                              \
  do {                                                                              \
    sg0 = *(const short8*)(kb + ((unsigned)bh * 1024 + (unsigned)(J0) + srow) * 64 + kgcol);      \
    sg1 = *(const short8*)(kb + ((unsigned)bh * 1024 + (unsigned)(J0) + srow + 8) * 64 + kgcol);  \
    sg2 = *(const short8*)(vt + ((unsigned)bh * 64 + srow) * 1024 + (unsigned)(J0) + kgcol);      \
    sg3 = *(const short8*)(vt + ((unsigned)bh * 64 + srow + 8) * 1024 + (unsigned)(J0) + kgcol);  \
  } while (0)
#define STAGE_WRITE(BUF)                                                            \
  do {                                                                              \
    char* KS_ = (char*)KV[BUF];                                                     \
    *(short8*)(KS_ + (unsigned)srow * 128 + sswz) = sg0;                            \
    *(short8*)(KS_ + (unsigned)(srow + 8) * 128 + sswz) = sg1;                      \
    *(short8*)(KS_ + 8192 + (unsigned)srow * 128 + sswz) = sg2;                     \
    *(short8*)(KS_ + 8192 + (unsigned)(srow + 8) * 128 + sswz) = sg3;               \
  } while (0)

#define RF_LOAD(RF, RBASE)                                                          \
  do {                                                                              \
    unsigned roff = (RBASE) + (unsigned)j0 * 64;                                    \
    _Pragma("unroll")                                                               \
    for (int f = 0; f < 5; ++f) {                                                   \
      RF[2 * f] = *(const short8*)(rhp + roff + f * 1024);                          \
      RF[2 * f + 1] = *(const short8*)(rhp + roff + f * 1024 + 32);                 \
    }                                                                               \
  } while (0)

#define KF_LOAD(KF)                                                                 \
  do {                                                                              \
    _Pragma("unroll")                                                               \
    for (int f = 0; f < 4; ++f) {                                                   \
      unsigned rowb = (unsigned)(f * 16 + fr) * 128;                                \
      KF[2 * f] = *(const short8*)(KS + rowb + (((unsigned)fkq * 2) ^ swzr));       \
      KF[2 * f + 1] = *(const short8*)(KS + rowb + (((unsigned)fkq * 2 + 64) ^ swzr)); \
    }                                                                               \
  } while (0)

#define VF_LOAD(VF)                                                                 \
  do {                                                                              \
    _Pragma("unroll")                                                               \
    for (int dg = 0; dg < 4; ++dg) {                                                \
      unsigned rowb = 8192 + (unsigned)(dg * 16 + fr) * 128;                        \
      VF[2 * dg] = *(const short8*)(KS + rowb + (((unsigned)fkq * 2) ^ swzr));      \
      VF[2 * dg + 1] = *(const short8*)(KS + rowb + (((unsigned)(64 + fkq * 2)) ^ swzr)); \
    }                                                                               \
  } while (0)

#define SCORE(AC, PB, KF, RF, AQW0, AQW1, AQR0, AQR1)                               \
  do {                                                                              \
    __builtin_amdgcn_s_setprio(1);                                                  \
    _Pragma("unroll")                                                               \
    for (int f = 0; f < 4; ++f) {                                                   \
      AC[f] = MFMA_BF16(AQW0, KF[2 * f], AC[f]);                                    \
      AC[f] = MFMA_BF16(AQW1, KF[2 * f + 1], AC[f]);                                \
    }                                                                               \
    _Pragma("unroll")                                                               \
    for (int f = 0; f < 5; ++f) {                                                   \
      PB[f] = MFMA_BF16(AQR0, RF[2 * f], PB[f]);                                    \
      PB[f] = MFMA_BF16(AQR1, RF[2 * f + 1], PB[f]);                                \
    }                                                                               \
    __builtin_amdgcn_s_setprio(0);                                                  \
  } while (0)

#define GATHER(AC, PB, IST, SRUN, PW)                                               \
  do {                                                                              \
    _Pragma("unroll")                                                               \
    for (int q = 0; q < 4; ++q) {                                                   \
      int ri = 4 * (l >> 4) + q;                                                    \
      int e = 15 + fr - ri;                                                         \
      int src = (l & 48) | (e & 15);                                                \
      float sh[5];                                                                  \
      _Pragma("unroll")                                                             \
      for (int f = 0; f < 5; ++f) sh[f] = __shfl(PB[f][q], src, 64);                \
      int hi = e >> 4;                                                              \
      int ig = (IST) + ri;                                                          \
      _Pragma("unroll")                                                             \
      for (int ni = 0; ni < 4; ++ni) {                                              \
        float pv = hi ? sh[ni + 1] : sh[ni];                                        \
        float s = (AC[ni][q] + pv) * scale - 20.0f;                                 \
        int jg = j0 + ni * 16 + fr;                                                 \
        float pp = (jg > ig) ? 0.f : __expf(s);                                     \
        *(ushort_t*)((PW) + (((ri * 128) + (ni * 16 + fr) * 2) ^ ((ri & 7) << 4))) = f2bf(pp); \
        SRUN[q] += pp;                                                              \
      }                                                                             \
    }                                                                               \
  } while (0)

#define PVACC(OACC, PW, VF)                                                         \
  do {                                                                              \
    short8 pa0 = *(const short8*)((PW) + ((fr * 128 + fkq * 2) ^ ((fr & 7) << 4))); \
    short8 pa1 = *(const short8*)((PW) + ((fr * 128 + 64 + fkq * 2) ^ ((fr & 7) << 4))); \
    __builtin_amdgcn_s_setprio(1);                                                  \
    _Pragma("unroll")                                                               \
    for (int dg = 0; dg < 4; ++dg) {                                                \
      OACC[dg] = MFMA_BF16(pa0, VF[2 * dg], OACC[dg]);                              \
      OACC[dg] = MFMA_BF16(pa1, VF[2 * dg + 1], OACC[dg]);                          \
    }                                                                               \
    __builtin_amdgcn_s_setprio(0);                                                  \
  } while (0)

  // prologue: stage tile 0
  STAGE_LOAD(0);
  STAGE_WRITE(0);
  __syncthreads();

  for (int jt = 0; jt < njt; ++jt) {
    const int j0 = jt << 6;
    const char* KS = (const char*)KV[jt & 1];

    if (jt + 1 < njt) STAGE_LOAD((jt + 1) << 6);

    if (jt < njtB) {
      // dual tile: two independent chains; B's ops slot into A's latency gaps
      short8 rfA[10];
      RF_LOAD(rfA, rbaseA);
      short8 kfA[8];
      KF_LOAD(kfA);
      f32x4 acA[4] = {};
      f32x4 pbA[5] = {};
      SCORE(acA, pbA, kfA, rfA, aqwA0, aqwA1, aqrA0, aqrA1);
      short8 rfB[10];
      RF_LOAD(rfB, rbaseB);                 // latency covered by GATHER-A below
      short8 vf[8];
      VF_LOAD(vf);
      GATHER(acA, pbA, istA, sA, PwA);
      short8 kfB[8];
      KF_LOAD(kfB);
      f32x4 acB[4] = {};
      f32x4 pbB[5] = {};
      SCORE(acB, pbB, kfB, rfB, aqwB0, aqwB1, aqrB0, aqrB1);
      GATHER(acB, pbB, istB, sB, PwB);
      PVACC(oA, PwA, vf);
      PVACC(oB, PwB, vf);
    } else {
      short8 rfA[10];
      RF_LOAD(rfA, rbaseA);
      short8 kfA[8];
      KF_LOAD(kfA);
      f32x4 acA[4] = {};
      f32x4 pbA[5] = {};
      SCORE(acA, pbA, kfA, rfA, aqwA0, aqwA1, aqrA0, aqrA1);
      short8 vf[8];
      VF_LOAD(vf);
      GATHER(acA, pbA, istA, sA, PwA);
      PVACC(oA, PwA, vf);
    }

    if (jt + 1 < njt) STAGE_WRITE((jt + 1) & 1);
    __syncthreads();
  }

  // ---- epilogue ----
#pragma unroll
  for (int q = 0; q < 4; ++q) {
    float a = sA[q], bq = sB[q];
#pragma unroll
    for (int o2 = 8; o2; o2 >>= 1) {
      a += __shfl_xor(a, o2, 64);
      bq += __shfl_xor(bq, o2, 64);
    }
    sA[q] = a;
    sB[q] = bq;
  }
#pragma unroll
  for (int dg = 0; dg < 4; ++dg) {
#pragma unroll
    for (int q = 0; q < 4; ++q) {
      int dd = dg * 16 + fr;
      int igA = istA + 4 * (l >> 4) + q;
      ctx[((size_t)igA * BATCH + b) * EMB + h * 64 + dd] = f2bf(oA[dg][q] / sA[q]);
      int igB = istB + 4 * (l >> 4) + q;
      ctx[((size_t)igB * BATCH + b) * EMB + h * 64 + dd] = f2bf(oB[dg][q] / sB[q]);
    }
  }
}

// ---------------- launch ----------------
extern "C" void kernel_launch(void* const* d_in, const int* in_sizes, int n_in,
                              void* d_out, int out_size, void* d_ws, size_t ws_size,
                              hipStream_t stream) {
  (void)in_sizes; (void)n_in; (void)out_size; (void)ws_size;
  const float* x = (const float*)d_in[0];
  const float* pos = (const float*)d_in[1];
  const float* in_w_mu = (const float*)d_in[3];
  const float* in_w_rho = (const float*)d_in[4];
  const float* in_w_eps = (const float*)d_in[5];
  const float* in_b_mu = (const float*)d_in[6];
  const float* in_b_rho = (const float*)d_in[7];
  const float* in_b_eps = (const float*)d_in[8];
  const float* pos_w_mu = (const float*)d_in[9];
  const float* pos_w_rho = (const float*)d_in[10];
  const float* pos_w_eps = (const float*)d_in[11];
  const float* pos_b_mu = (const float*)d_in[12];
  const float* pos_b_rho = (const float*)d_in[13];
  const float* pos_b_eps = (const float*)d_in[14];
  const float* out_w_mu = (const float*)d_in[15];
  const float* out_w_rho = (const float*)d_in[16];
  const float* out_w_eps = (const float*)d_in[17];
  const float* out_b_mu = (const float*)d_in[18];
  const float* out_b_rho = (const float*)d_in[19];
  const float* out_b_eps = (const float*)d_in[20];
  const float* rw_mu = (const float*)d_in[21];
  const float* rw_rho = (const float*)d_in[22];
  const float* rw_eps = (const float*)d_in[23];
  const float* rr_mu = (const float*)d_in[24];
  const float* rr_rho = (const float*)d_in[25];
  const float* rr_eps = (const float*)d_in[26];

  char* ws = (char*)d_ws;
  ushort_t* in_w_bf  = (ushort_t*)(ws + 0);
  ushort_t* pos_w_bf = (ushort_t*)(ws + 6291456);
  ushort_t* out_w_bf = (ushort_t*)(ws + 8388608);
  float* in_b  = (float*)(ws + 10485760);
  float* pos_b = (float*)(ws + 10498048);
  float* out_b = (float*)(ws + 10502144);
  float* rwb   = (float*)(ws + 10506240);
  float* rrb   = (float*)(ws + 10510336);
  ushort_t* x_bf    = (ushort_t*)(ws + 10514432);
  ushort_t* posx_bf = (ushort_t*)(ws + 18903040);
  ushort_t* qrw = (ushort_t*)(ws + 21000192);
  ushort_t* qrr = (ushort_t*)(ws + 29388800);
  ushort_t* kb  = (ushort_t*)(ws + 37777408);
  ushort_t* vt  = (ushort_t*)(ws + 46166016);
  ushort_t* rhp = (ushort_t*)(ws + 54554624);
  ushort_t* ctx = (ushort_t*)(ws + 56913920);

  sample_w_kernel<<<5120, 256, 0, stream>>>(in_w_mu, in_w_rho, in_w_eps, in_w_bf,
                                            pos_w_mu, pos_w_rho, pos_w_eps, pos_w_bf,
                                            out_w_mu, out_w_rho, out_w_eps, out_w_bf);
  sample_bias_kernel<<<28, 256, 0, stream>>>(in_b_mu, in_b_rho, in_b_eps, in_b,
                                             pos_b_mu, pos_b_rho, pos_b_eps, pos_b,
                                             out_b_mu, out_b_rho, out_b_eps, out_b,
                                             rw_mu, rw_rho, rw_eps, rwb,
                                             rr_mu, rr_rho, rr_eps, rrb);
  cast_bf16x4_kernel<<<4096, 256, 0, stream>>>(x, x_bf, 1048576);
  cast_bf16x4_kernel<<<1024, 256, 0, stream>>>(pos, posx_bf, 262144);
  zero_rhp_pad_kernel<<<512, 256, 0, stream>>>(rhp);

  gemm_qkvpos_kernel<<<832, 256, 0, stream>>>(x_bf, in_w_bf, in_b, rwb, rrb,
                                              posx_bf, pos_w_bf, pos_b,
                                              qrw, qrr, kb, vt, rhp);

  attn_kernel<<<dim3(512), 256, 0, stream>>>(qrw, qrr, kb, vt, rhp, ctx);

  gemm_bt_kernel<<<dim3(32, 8), 256, 0, stream>>>(ctx, out_w_bf, out_b, (float*)d_out, 4096, 1024, 1024);
}

// Round 17
// 206.385 us; speedup vs baseline: 1.9625x; 1.7631x over previous
//
#include <hip/hip_runtime.h>

typedef unsigned short ushort_t;
typedef __attribute__((ext_vector_type(8))) short short8;
typedef __attribute__((ext_vector_type(4))) float f32x4;
typedef __attribute__((ext_vector_type(4))) unsigned short ush4;

#define MFMA_BF16(a, b, c) __builtin_amdgcn_mfma_f32_16x16x32_bf16((a), (b), (c), 0, 0, 0)

#define GLOAD_LDS16(GP, LP)                                                       \
  __builtin_amdgcn_global_load_lds(                                               \
      (const __attribute__((address_space(1))) void*)(GP),                        \
      (__attribute__((address_space(3))) void*)(LP), 16, 0, 0)

#define T_LEN 1024
#define BATCH 4
#define NHEAD 16
#define DHEAD 64
#define EMB 1024

__device__ __forceinline__ ushort_t f2bf(float f) {
  unsigned u = __float_as_uint(f);
  u += 0x7fffu + ((u >> 16) & 1u);
  return (ushort_t)(u >> 16);
}

// ---------------- elementwise ----------------
__global__ void sample_w_kernel(const float* __restrict__ im, const float* __restrict__ ir,
                                const float* __restrict__ ie, ushort_t* __restrict__ io,
                                const float* __restrict__ pm, const float* __restrict__ pr,
                                const float* __restrict__ pe, ushort_t* __restrict__ po,
                                const float* __restrict__ om, const float* __restrict__ orh,
                                const float* __restrict__ oe, ushort_t* __restrict__ oo) {
  int i = blockIdx.x * 256 + threadIdx.x;
  const float *mu, *rho, *eps;
  ushort_t* out;
  int j;
  if (i < 786432) { mu = im; rho = ir; eps = ie; out = io; j = i; }
  else if (i < 1048576) { mu = pm; rho = pr; eps = pe; out = po; j = i - 786432; }
  else { mu = om; rho = orh; eps = oe; out = oo; j = i - 1048576; }
  f32x4 m = *(const f32x4*)(mu + (size_t)j * 4);
  f32x4 r = *(const f32x4*)(rho + (size_t)j * 4);
  f32x4 e = *(const f32x4*)(eps + (size_t)j * 4);
  ush4 o;
#pragma unroll
  for (int k = 0; k < 4; ++k) o[k] = f2bf(m[k] + log1pf(__expf(r[k])) * e[k]);
  *(ush4*)(out + (size_t)j * 4) = o;
}

__global__ void sample_bias_kernel(
    const float* __restrict__ am, const float* __restrict__ ar, const float* __restrict__ ae, float* __restrict__ ao,
    const float* __restrict__ bm, const float* __restrict__ br, const float* __restrict__ be, float* __restrict__ bo,
    const float* __restrict__ cm, const float* __restrict__ cr, const float* __restrict__ ce, float* __restrict__ co,
    const float* __restrict__ dm, const float* __restrict__ dr, const float* __restrict__ de, float* __restrict__ dof,
    const float* __restrict__ em, const float* __restrict__ er, const float* __restrict__ ee, float* __restrict__ eo) {
  int i = blockIdx.x * 256 + threadIdx.x;
  if (i < 3072) {
    ao[i] = am[i] + log1pf(__expf(ar[i])) * ae[i];
  } else if (i < 4096) {
    int j = i - 3072; bo[j] = bm[j] + log1pf(__expf(br[j])) * be[j];
  } else if (i < 5120) {
    int j = i - 4096; co[j] = cm[j] + log1pf(__expf(cr[j])) * ce[j];
  } else if (i < 6144) {
    int j = i - 5120; dof[j] = dm[j] + log1pf(__expf(dr[j])) * de[j];
  } else if (i < 7168) {
    int j = i - 6144; eo[j] = em[j] + log1pf(__expf(er[j])) * ee[j];
  }
}

__global__ void cast_bf16x4_kernel(const float* __restrict__ in, ushort_t* __restrict__ out, int n4) {
  int i = blockIdx.x * 256 + threadIdx.x;
  if (i < n4) {
    f32x4 v = *(const f32x4*)(in + (size_t)i * 4);
    ush4 o;
#pragma unroll
    for (int j = 0; j < 4; ++j) o[j] = f2bf(v[j]);
    *(ush4*)(out + (size_t)i * 4) = o;
  }
}

__global__ void zero_rhp_pad_kernel(ushort_t* __restrict__ rhp) {
  int idx = blockIdx.x * 256 + threadIdx.x;
  int dd = idx & 63;
  int pr = (idx >> 6) & 127;
  int h = idx >> 13;
  int phys = (pr < 64) ? pr : (pr - 64 + 1088);
  rhp[((size_t)h * 1152 + phys) * 64 + dd] = 0;
}

// ---------------- GEMM (out-proj) ----------------
__global__ __launch_bounds__(256, 2)
void gemm_bt_kernel(const ushort_t* __restrict__ A, const ushort_t* __restrict__ Bt,
                    const float* __restrict__ bias, float* __restrict__ C,
                    int M, int N, int K) {
  __shared__ ushort_t As[128 * 32];
  __shared__ ushort_t Bs[128 * 32];
  const int tid = threadIdx.x;
  const int w = tid >> 6, l = tid & 63;
  const int m0 = blockIdx.x * 128, n0 = blockIdx.y * 128;
  const int wr = w >> 1, wc = w & 1;
  const int fr = l & 15, fk = (l >> 4) * 8;

  f32x4 acc[4][4] = {};

  for (int k0 = 0; k0 < K; k0 += 32) {
    __syncthreads();
#pragma unroll
    for (int p = 0; p < 2; ++p) {
      int c = p * 256 + tid;
      int row = c >> 2, col = (c & 3) * 8;
      GLOAD_LDS16(&A[(size_t)(m0 + row) * K + k0 + col], &As[c * 8]);
      GLOAD_LDS16(&Bt[(size_t)(n0 + row) * K + k0 + col], &Bs[c * 8]);
    }
    __syncthreads();
    short8 af[4], bf[4];
#pragma unroll
    for (int mi = 0; mi < 4; ++mi) af[mi] = *(const short8*)(&As[(wr * 64 + mi * 16 + fr) * 32 + fk]);
#pragma unroll
    for (int ni = 0; ni < 4; ++ni) bf[ni] = *(const short8*)(&Bs[(wc * 64 + ni * 16 + fr) * 32 + fk]);
#pragma unroll
    for (int mi = 0; mi < 4; ++mi)
#pragma unroll
      for (int ni = 0; ni < 4; ++ni)
        acc[mi][ni] = MFMA_BF16(af[mi], bf[ni], acc[mi][ni]);
  }

#pragma unroll
  for (int ni = 0; ni < 4; ++ni) {
    int col = n0 + wc * 64 + ni * 16 + fr;
    float bv = bias[col];
#pragma unroll
    for (int mi = 0; mi < 4; ++mi) {
#pragma unroll
      for (int q = 0; q < 4; ++q) {
        int row = m0 + wr * 64 + mi * 16 + (l >> 4) * 4 + q;
        C[(size_t)row * N + col] = acc[mi][ni][q] + bv;
      }
    }
  }
}

// ---------------- merged QKV + pos GEMM ----------------
__global__ __launch_bounds__(256, 2)
void gemm_qkvpos_kernel(const ushort_t* __restrict__ x_bf, const ushort_t* __restrict__ in_w_bf,
                        const float* __restrict__ in_b,
                        const float* __restrict__ rwb, const float* __restrict__ rrb,
                        const ushort_t* __restrict__ posx_bf, const ushort_t* __restrict__ pos_w_bf,
                        const float* __restrict__ pos_b,
                        ushort_t* __restrict__ qrw, ushort_t* __restrict__ qrr,
                        ushort_t* __restrict__ kbuf, ushort_t* __restrict__ vt,
                        ushort_t* __restrict__ rhp) {
  __shared__ ushort_t As[128 * 32];
  __shared__ ushort_t Bs[128 * 32];
  const int K = 1024;
  const int tid = threadIdx.x;
  const int w = tid >> 6, l = tid & 63;
  const int bid = blockIdx.x;
  const bool isPos = bid >= 768;
  int m0, n0;
  const ushort_t *A, *Bt;
  if (!isPos) {
    m0 = (bid & 31) * 128; n0 = (bid >> 5) * 128; A = x_bf; Bt = in_w_bf;
  } else {
    int pb2 = bid - 768;
    m0 = (pb2 & 7) * 128; n0 = (pb2 >> 3) * 128; A = posx_bf; Bt = pos_w_bf;
  }
  const int wr = w >> 1, wc = w & 1;
  const int fr = l & 15, fk = (l >> 4) * 8;

  f32x4 acc[4][4] = {};

  for (int k0 = 0; k0 < K; k0 += 32) {
    __syncthreads();
#pragma unroll
    for (int p = 0; p < 2; ++p) {
      int c = p * 256 + tid;
      int row = c >> 2, col = (c & 3) * 8;
      GLOAD_LDS16(&A[(size_t)(m0 + row) * K + k0 + col], &As[c * 8]);
      GLOAD_LDS16(&Bt[(size_t)(n0 + row) * K + k0 + col], &Bs[c * 8]);
    }
    __syncthreads();
    short8 af[4], bf[4];
#pragma unroll
    for (int mi = 0; mi < 4; ++mi) af[mi] = *(const short8*)(&As[(wr * 64 + mi * 16 + fr) * 32 + fk]);
#pragma unroll
    for (int ni = 0; ni < 4; ++ni) bf[ni] = *(const short8*)(&Bs[(wc * 64 + ni * 16 + fr) * 32 + fk]);
#pragma unroll
    for (int mi = 0; mi < 4; ++mi)
#pragma unroll
      for (int ni = 0; ni < 4; ++ni)
        acc[mi][ni] = MFMA_BF16(af[mi], bf[ni], acc[mi][ni]);
  }

  if (!isPos) {
#pragma unroll
    for (int ni = 0; ni < 4; ++ni) {
      int col = n0 + wc * 64 + ni * 16 + fr;
      int part = col >> 10;
      int e = col & 1023;
      int hh = e >> 6, dd = e & 63;
      float bv = in_b[col];
      float rwv = rwb[e];
      float rrv = rrb[e];
#pragma unroll
      for (int mi = 0; mi < 4; ++mi) {
#pragma unroll
        for (int q = 0; q < 4; ++q) {
          int row = m0 + wr * 64 + mi * 16 + (l >> 4) * 4 + q;
          int t = row >> 2, b = row & 3;
          float v = acc[mi][ni][q] + bv;
          if (part == 0) {
            unsigned idx = (((unsigned)(b * 16 + hh) * 1024 + t) << 6) + dd;
            qrw[idx] = f2bf(v + rwv);
            qrr[idx] = f2bf(v + rrv);
          } else if (part == 1) {
            unsigned idx = (((unsigned)(b * 16 + hh) * 1024 + t) << 6) + dd;
            kbuf[idx] = f2bf(v);
          } else {
            vt[(((unsigned)(b * 16 + hh) * 64 + dd) << 10) + t] = f2bf(v);
          }
        }
      }
    }
  } else {
#pragma unroll
    for (int ni = 0; ni < 4; ++ni) {
      int col = n0 + wc * 64 + ni * 16 + fr;
      int hh = col >> 6, dd = col & 63;
      float bv = pos_b[col];
#pragma unroll
      for (int mi = 0; mi < 4; ++mi) {
#pragma unroll
        for (int q = 0; q < 4; ++q) {
          int t = m0 + wr * 64 + mi * 16 + (l >> 4) * 4 + q;
          rhp[((unsigned)hh * 1152 + 64 + t) * 64 + dd] = f2bf(acc[mi][ni][q] + bv);
        }
      }
    }
  }
}

// ---------------- attn v7b: R14 v7 + separate P buffers per strip ----------------
// R16's hand-hoisted dual-chain spilled (~150 live transients -> 270MB scratch). v7b keeps
// R14's exact transient-in-macro structure (124 VGPR, clean) and applies ONLY the WAR fix:
// strip A and strip B get separate P-transpose buffers, so B's chain no longer waits on A's
// PV read of the shared buffer. Compiler is free to interleave the two independent chains.
__global__ __launch_bounds__(256, 2)
void attn_kernel(const ushort_t* __restrict__ qrw, const ushort_t* __restrict__ qrr,
                 const ushort_t* __restrict__ kb, const ushort_t* __restrict__ vt,
                 const ushort_t* __restrict__ rhp, ushort_t* __restrict__ ctx) {
  __shared__ __attribute__((aligned(16))) ushort_t KV[2][8192];  // 32KB
  __shared__ __attribute__((aligned(16))) char PtA[4][2048];     // strip-A P transpose, 8KB
  __shared__ __attribute__((aligned(16))) char PtBb[4][2048];    // strip-B P transpose, 8KB

  const int tid = threadIdx.x, w = tid >> 6, l = tid & 63;
  const int bid = blockIdx.x;
  const int g = bid & 63;
  const int h = ((g & 7) << 1) | ((g >> 3) & 1);
  const int b = g >> 4;
  const int bh = b * 16 + h;
  const int p = bid >> 6;
  const int istA = (15 - p) * 64 + w * 16;
  const int istB = p * 64 + w * 16;
  const int njt = 16 - p;
  const int njtB = p + 1;
  const int fr = l & 15, fkq = (l >> 4) * 8;
  const float scale = 0.125f;
  char* PwA = PtA[w];
  char* PwB = PtBb[w];

  short8 aqwA0, aqwA1, aqrA0, aqrA1, aqwB0, aqwB1, aqrB0, aqrB1;
  {
    unsigned qa = ((unsigned)bh * T_LEN + istA + fr) * 64 + fkq;
    aqwA0 = *(const short8*)(qrw + qa);
    aqwA1 = *(const short8*)(qrw + qa + 32);
    aqrA0 = *(const short8*)(qrr + qa);
    aqrA1 = *(const short8*)(qrr + qa + 32);
    unsigned qb = ((unsigned)bh * T_LEN + istB + fr) * 64 + fkq;
    aqwB0 = *(const short8*)(qrw + qb);
    aqwB1 = *(const short8*)(qrw + qb + 32);
    aqrB0 = *(const short8*)(qrr + qb);
    aqrB1 = *(const short8*)(qrr + qb + 32);
  }

  const int srow = 16 * w + (l >> 3);
  const unsigned sswz = (unsigned)(((l & 7) ^ (l >> 3)) << 4);
  const unsigned kgcol = (unsigned)(l & 7) * 8;
  const unsigned swzr = (unsigned)(fr & 7) << 4;

  const unsigned rbaseA = ((unsigned)h * 1152 + 64 + 1008 - istA + fr) * 64 + fkq;
  const unsigned rbaseB = ((unsigned)h * 1152 + 64 + 1008 - istB + fr) * 64 + fkq;

  float sA[4] = {0.f, 0.f, 0.f, 0.f}, sB[4] = {0.f, 0.f, 0.f, 0.f};
  f32x4 oA[4] = {}, oB[4] = {};

  short8 sg0, sg1, sg2, sg3;
#define STAGE_LOAD(J0)                                                              \
  do {                                                                              \
    sg0 = *(const short8*)(kb + ((unsigned)bh * 1024 + (unsigned)(J0) + srow) * 64 + kgcol);      \
    sg1 = *(const short8*)(kb + ((unsigned)bh * 1024 + (unsigned)(J0) + srow + 8) * 64 + kgcol);  \
    sg2 = *(const short8*)(vt + ((unsigned)bh * 64 + srow) * 1024 + (unsigned)(J0) + kgcol);      \
    sg3 = *(const short8*)(vt + ((unsigned)bh * 64 + srow + 8) * 1024 + (unsigned)(J0) + kgcol);  \
  } while (0)
#define STAGE_WRITE(BUF)                                                            \
  do {                                                                              \
    char* KS_ = (char*)KV[BUF];                                                     \
    *(short8*)(KS_ + (unsigned)srow * 128 + sswz) = sg0;                            \
    *(short8*)(KS_ + (unsigned)(srow + 8) * 128 + sswz) = sg1;                      \
    *(short8*)(KS_ + 8192 + (unsigned)srow * 128 + sswz) = sg2;                     \
    *(short8*)(KS_ + 8192 + (unsigned)(srow + 8) * 128 + sswz) = sg3;               \
  } while (0)

// identical to R14's STRIP_TILE except the P buffer is a parameter
#define STRIP_TILE(AQW0, AQW1, AQR0, AQR1, RBASE, IST, SRUN, OACC, PW)               \
  do {                                                                               \
    short8 rf[10];                                                                   \
    unsigned roff = (RBASE) + (unsigned)j0 * 64;                                     \
    _Pragma("unroll")                                                                \
    for (int f = 0; f < 5; ++f) {                                                    \
      rf[2 * f] = *(const short8*)(rhp + roff + f * 1024);                           \
      rf[2 * f + 1] = *(const short8*)(rhp + roff + f * 1024 + 32);                  \
    }                                                                                \
    f32x4 ac[4] = {};                                                                \
    f32x4 pb[5] = {};                                                                \
    {                                                                                \
      short8 kf[8];                                                                  \
      _Pragma("unroll")                                                              \
      for (int f = 0; f < 4; ++f) {                                                  \
        unsigned rowb = (unsigned)(f * 16 + fr) * 128;                               \
        kf[2 * f] = *(const short8*)(KS + rowb + (((unsigned)fkq * 2) ^ swzr));      \
        kf[2 * f + 1] = *(const short8*)(KS + rowb + (((unsigned)fkq * 2 + 64) ^ swzr)); \
      }                                                                              \
      __builtin_amdgcn_s_setprio(1);                                                 \
      _Pragma("unroll")                                                              \
      for (int f = 0; f < 4; ++f) {                                                  \
        ac[f] = MFMA_BF16(AQW0, kf[2 * f], ac[f]);                                   \
        ac[f] = MFMA_BF16(AQW1, kf[2 * f + 1], ac[f]);                               \
      }                                                                              \
      _Pragma("unroll")                                                              \
      for (int f = 0; f < 5; ++f) {                                                  \
        pb[f] = MFMA_BF16(AQR0, rf[2 * f], pb[f]);                                   \
        pb[f] = MFMA_BF16(AQR1, rf[2 * f + 1], pb[f]);                               \
      }                                                                              \
      __builtin_amdgcn_s_setprio(0);                                                 \
    }                                                                                \
    _Pragma("unroll")                                                                \
    for (int q = 0; q < 4; ++q) {                                                    \
      int ri = 4 * (l >> 4) + q;                                                     \
      int e = 15 + fr - ri;                                                          \
      int src = (l & 48) | (e & 15);                                                 \
      float sh[5];                                                                   \
      _Pragma("unroll")                                                              \
      for (int f = 0; f < 5; ++f) sh[f] = __shfl(pb[f][q], src, 64);                 \
      int hi = e >> 4;                                                               \
      int ig = (IST) + ri;                                                           \
      _Pragma("unroll")                                                              \
      for (int ni = 0; ni < 4; ++ni) {                                               \
        float pv = hi ? sh[ni + 1] : sh[ni];                                         \
        float s = (ac[ni][q] + pv) * scale - 20.0f;                                  \
        int jg = j0 + ni * 16 + fr;                                                  \
        float pp = (jg > ig) ? 0.f : __expf(s);                                      \
        *(ushort_t*)((PW) + (((ri * 128) + (ni * 16 + fr) * 2) ^ ((ri & 7) << 4))) = f2bf(pp); \
        SRUN[q] += pp;                                                               \
      }                                                                              \
    }                                                                                \
    {                                                                                \
      short8 vf[8];                                                                  \
      _Pragma("unroll")                                                              \
      for (int dg = 0; dg < 4; ++dg) {                                               \
        unsigned rowb = 8192 + (unsigned)(dg * 16 + fr) * 128;                       \
        vf[2 * dg] = *(const short8*)(KS + rowb + (((unsigned)fkq * 2) ^ swzr));     \
        vf[2 * dg + 1] = *(const short8*)(KS + rowb + (((unsigned)(64 + fkq * 2)) ^ swzr)); \
      }                                                                              \
      short8 pa0 = *(const short8*)((PW) + ((fr * 128 + fkq * 2) ^ ((fr & 7) << 4))); \
      short8 pa1 = *(const short8*)((PW) + ((fr * 128 + 64 + fkq * 2) ^ ((fr & 7) << 4))); \
      __builtin_amdgcn_s_setprio(1);                                                 \
      _Pragma("unroll")                                                              \
      for (int dg = 0; dg < 4; ++dg) {                                               \
        OACC[dg] = MFMA_BF16(pa0, vf[2 * dg], OACC[dg]);                             \
        OACC[dg] = MFMA_BF16(pa1, vf[2 * dg + 1], OACC[dg]);                         \
      }                                                                              \
      __builtin_amdgcn_s_setprio(0);                                                 \
    }                                                                                \
  } while (0)

  // prologue: stage tile 0
  STAGE_LOAD(0);
  STAGE_WRITE(0);
  __syncthreads();

  for (int jt = 0; jt < njt; ++jt) {
    const int j0 = jt << 6;
    const char* KS = (const char*)KV[jt & 1];

    if (jt + 1 < njt) STAGE_LOAD((jt + 1) << 6);

    STRIP_TILE(aqwA0, aqwA1, aqrA0, aqrA1, rbaseA, istA, sA, oA, PwA);
    if (jt < njtB) STRIP_TILE(aqwB0, aqwB1, aqrB0, aqrB1, rbaseB, istB, sB, oB, PwB);

    if (jt + 1 < njt) STAGE_WRITE((jt + 1) & 1);
    __syncthreads();
  }

  // ---- epilogue ----
#pragma unroll
  for (int q = 0; q < 4; ++q) {
    float a = sA[q], bq = sB[q];
#pragma unroll
    for (int o2 = 8; o2; o2 >>= 1) {
      a += __shfl_xor(a, o2, 64);
      bq += __shfl_xor(bq, o2, 64);
    }
    sA[q] = a;
    sB[q] = bq;
  }
#pragma unroll
  for (int dg = 0; dg < 4; ++dg) {
#pragma unroll
    for (int q = 0; q < 4; ++q) {
      int dd = dg * 16 + fr;
      int igA = istA + 4 * (l >> 4) + q;
      ctx[((size_t)igA * BATCH + b) * EMB + h * 64 + dd] = f2bf(oA[dg][q] / sA[q]);
      int igB = istB + 4 * (l >> 4) + q;
      ctx[((size_t)igB * BATCH + b) * EMB + h * 64 + dd] = f2bf(oB[dg][q] / sB[q]);
    }
  }
}

// ---------------- launch ----------------
extern "C" void kernel_launch(void* const* d_in, const int* in_sizes, int n_in,
                              void* d_out, int out_size, void* d_ws, size_t ws_size,
                              hipStream_t stream) {
  (void)in_sizes; (void)n_in; (void)out_size; (void)ws_size;
  const float* x = (const float*)d_in[0];
  const float* pos = (const float*)d_in[1];
  const float* in_w_mu = (const float*)d_in[3];
  const float* in_w_rho = (const float*)d_in[4];
  const float* in_w_eps = (const float*)d_in[5];
  const float* in_b_mu = (const float*)d_in[6];
  const float* in_b_rho = (const float*)d_in[7];
  const float* in_b_eps = (const float*)d_in[8];
  const float* pos_w_mu = (const float*)d_in[9];
  const float* pos_w_rho = (const float*)d_in[10];
  const float* pos_w_eps = (const float*)d_in[11];
  const float* pos_b_mu = (const float*)d_in[12];
  const float* pos_b_rho = (const float*)d_in[13];
  const float* pos_b_eps = (const float*)d_in[14];
  const float* out_w_mu = (const float*)d_in[15];
  const float* out_w_rho = (const float*)d_in[16];
  const float* out_w_eps = (const float*)d_in[17];
  const float* out_b_mu = (const float*)d_in[18];
  const float* out_b_rho = (const float*)d_in[19];
  const float* out_b_eps = (const float*)d_in[20];
  const float* rw_mu = (const float*)d_in[21];
  const float* rw_rho = (const float*)d_in[22];
  const float* rw_eps = (const float*)d_in[23];
  const float* rr_mu = (const float*)d_in[24];
  const float* rr_rho = (const float*)d_in[25];
  const float* rr_eps = (const float*)d_in[26];

  char* ws = (char*)d_ws;
  ushort_t* in_w_bf  = (ushort_t*)(ws + 0);
  ushort_t* pos_w_bf = (ushort_t*)(ws + 6291456);
  ushort_t* out_w_bf = (ushort_t*)(ws + 8388608);
  float* in_b  = (float*)(ws + 10485760);
  float* pos_b = (float*)(ws + 10498048);
  float* out_b = (float*)(ws + 10502144);
  float* rwb   = (float*)(ws + 10506240);
  float* rrb   = (float*)(ws + 10510336);
  ushort_t* x_bf    = (ushort_t*)(ws + 10514432);
  ushort_t* posx_bf = (ushort_t*)(ws + 18903040);
  ushort_t* qrw = (ushort_t*)(ws + 21000192);
  ushort_t* qrr = (ushort_t*)(ws + 29388800);
  ushort_t* kb  = (ushort_t*)(ws + 37777408);
  ushort_t* vt  = (ushort_t*)(ws + 46166016);
  ushort_t* rhp = (ushort_t*)(ws + 54554624);
  ushort_t* ctx = (ushort_t*)(ws + 56913920);

  sample_w_kernel<<<5120, 256, 0, stream>>>(in_w_mu, in_w_rho, in_w_eps, in_w_bf,
                                            pos_w_mu, pos_w_rho, pos_w_eps, pos_w_bf,
                                            out_w_mu, out_w_rho, out_w_eps, out_w_bf);
  sample_bias_kernel<<<28, 256, 0, stream>>>(in_b_mu, in_b_rho, in_b_eps, in_b,
                                             pos_b_mu, pos_b_rho, pos_b_eps, pos_b,
                                             out_b_mu, out_b_rho, out_b_eps, out_b,
                                             rw_mu, rw_rho, rw_eps, rwb,
                                             rr_mu, rr_rho, rr_eps, rrb);
  cast_bf16x4_kernel<<<4096, 256, 0, stream>>>(x, x_bf, 1048576);
  cast_bf16x4_kernel<<<1024, 256, 0, stream>>>(pos, posx_bf, 262144);
  zero_rhp_pad_kernel<<<512, 256, 0, stream>>>(rhp);

  gemm_qkvpos_kernel<<<832, 256, 0, stream>>>(x_bf, in_w_bf, in_b, rwb, rrb,
                                              posx_bf, pos_w_bf, pos_b,
                                              qrw, qrr, kb, vt, rhp);

  attn_kernel<<<dim3(512), 256, 0, stream>>>(qrw, qrr, kb, vt, rhp, ctx);

  gemm_bt_kernel<<<dim3(32, 8), 256, 0, stream>>>(ctx, out_w_bf, out_b, (float*)d_out, 4096, 1024, 1024);
}

// Round 18
// 202.838 us; speedup vs baseline: 1.9968x; 1.0175x over previous
//
#include <hip/hip_runtime.h>

typedef unsigned short ushort_t;
typedef __attribute__((ext_vector_type(8))) short short8;
typedef __attribute__((ext_vector_type(4))) float f32x4;
typedef __attribute__((ext_vector_type(4))) unsigned short ush4;

#define MFMA_BF16(a, b, c) __builtin_amdgcn_mfma_f32_16x16x32_bf16((a), (b), (c), 0, 0, 0)

#define GLOAD_LDS16(GP, LP)                                                       \
  __builtin_amdgcn_global_load_lds(                                               \
      (const __attribute__((address_space(1))) void*)(GP),                        \
      (__attribute__((address_space(3))) void*)(LP), 16, 0, 0)

#define T_LEN 1024
#define BATCH 4
#define NHEAD 16
#define DHEAD 64
#define EMB 1024

__device__ __forceinline__ ushort_t f2bf(float f) {
  unsigned u = __float_as_uint(f);
  u += 0x7fffu + ((u >> 16) & 1u);
  return (ushort_t)(u >> 16);
}

// ---------------- elementwise ----------------
__global__ void sample_w_kernel(const float* __restrict__ im, const float* __restrict__ ir,
                                const float* __restrict__ ie, ushort_t* __restrict__ io,
                                const float* __restrict__ pm, const float* __restrict__ pr,
                                const float* __restrict__ pe, ushort_t* __restrict__ po,
                                const float* __restrict__ om, const float* __restrict__ orh,
                                const float* __restrict__ oe, ushort_t* __restrict__ oo) {
  int i = blockIdx.x * 256 + threadIdx.x;
  const float *mu, *rho, *eps;
  ushort_t* out;
  int j;
  if (i < 786432) { mu = im; rho = ir; eps = ie; out = io; j = i; }
  else if (i < 1048576) { mu = pm; rho = pr; eps = pe; out = po; j = i - 786432; }
  else { mu = om; rho = orh; eps = oe; out = oo; j = i - 1048576; }
  f32x4 m = *(const f32x4*)(mu + (size_t)j * 4);
  f32x4 r = *(const f32x4*)(rho + (size_t)j * 4);
  f32x4 e = *(const f32x4*)(eps + (size_t)j * 4);
  ush4 o;
#pragma unroll
  for (int k = 0; k < 4; ++k) o[k] = f2bf(m[k] + log1pf(__expf(r[k])) * e[k]);
  *(ush4*)(out + (size_t)j * 4) = o;
}

__global__ void sample_bias_kernel(
    const float* __restrict__ am, const float* __restrict__ ar, const float* __restrict__ ae, float* __restrict__ ao,
    const float* __restrict__ bm, const float* __restrict__ br, const float* __restrict__ be, float* __restrict__ bo,
    const float* __restrict__ cm, const float* __restrict__ cr, const float* __restrict__ ce, float* __restrict__ co,
    const float* __restrict__ dm, const float* __restrict__ dr, const float* __restrict__ de, float* __restrict__ dof,
    const float* __restrict__ em, const float* __restrict__ er, const float* __restrict__ ee, float* __restrict__ eo) {
  int i = blockIdx.x * 256 + threadIdx.x;
  if (i < 3072) {
    ao[i] = am[i] + log1pf(__expf(ar[i])) * ae[i];
  } else if (i < 4096) {
    int j = i - 3072; bo[j] = bm[j] + log1pf(__expf(br[j])) * be[j];
  } else if (i < 5120) {
    int j = i - 4096; co[j] = cm[j] + log1pf(__expf(cr[j])) * ce[j];
  } else if (i < 6144) {
    int j = i - 5120; dof[j] = dm[j] + log1pf(__expf(dr[j])) * de[j];
  } else if (i < 7168) {
    int j = i - 6144; eo[j] = em[j] + log1pf(__expf(er[j])) * ee[j];
  }
}

__global__ void cast_bf16x4_kernel(const float* __restrict__ in, ushort_t* __restrict__ out, int n4) {
  int i = blockIdx.x * 256 + threadIdx.x;
  if (i < n4) {
    f32x4 v = *(const f32x4*)(in + (size_t)i * 4);
    ush4 o;
#pragma unroll
    for (int j = 0; j < 4; ++j) o[j] = f2bf(v[j]);
    *(ush4*)(out + (size_t)i * 4) = o;
  }
}

__global__ void zero_rhp_pad_kernel(ushort_t* __restrict__ rhp) {
  int idx = blockIdx.x * 256 + threadIdx.x;
  int dd = idx & 63;
  int pr = (idx >> 6) & 127;
  int h = idx >> 13;
  int phys = (pr < 64) ? pr : (pr - 64 + 1088);
  rhp[((size_t)h * 1152 + phys) * 64 + dd] = 0;
}

// ---------------- GEMM (out-proj) ----------------
__global__ __launch_bounds__(256, 2)
void gemm_bt_kernel(const ushort_t* __restrict__ A, const ushort_t* __restrict__ Bt,
                    const float* __restrict__ bias, float* __restrict__ C,
                    int M, int N, int K) {
  __shared__ ushort_t As[128 * 32];
  __shared__ ushort_t Bs[128 * 32];
  const int tid = threadIdx.x;
  const int w = tid >> 6, l = tid & 63;
  const int m0 = blockIdx.x * 128, n0 = blockIdx.y * 128;
  const int wr = w >> 1, wc = w & 1;
  const int fr = l & 15, fk = (l >> 4) * 8;

  f32x4 acc[4][4] = {};

  for (int k0 = 0; k0 < K; k0 += 32) {
    __syncthreads();
#pragma unroll
    for (int p = 0; p < 2; ++p) {
      int c = p * 256 + tid;
      int row = c >> 2, col = (c & 3) * 8;
      GLOAD_LDS16(&A[(size_t)(m0 + row) * K + k0 + col], &As[c * 8]);
      GLOAD_LDS16(&Bt[(size_t)(n0 + row) * K + k0 + col], &Bs[c * 8]);
    }
    __syncthreads();
    short8 af[4], bf[4];
#pragma unroll
    for (int mi = 0; mi < 4; ++mi) af[mi] = *(const short8*)(&As[(wr * 64 + mi * 16 + fr) * 32 + fk]);
#pragma unroll
    for (int ni = 0; ni < 4; ++ni) bf[ni] = *(const short8*)(&Bs[(wc * 64 + ni * 16 + fr) * 32 + fk]);
#pragma unroll
    for (int mi = 0; mi < 4; ++mi)
#pragma unroll
      for (int ni = 0; ni < 4; ++ni)
        acc[mi][ni] = MFMA_BF16(af[mi], bf[ni], acc[mi][ni]);
  }

#pragma unroll
  for (int ni = 0; ni < 4; ++ni) {
    int col = n0 + wc * 64 + ni * 16 + fr;
    float bv = bias[col];
#pragma unroll
    for (int mi = 0; mi < 4; ++mi) {
#pragma unroll
      for (int q = 0; q < 4; ++q) {
        int row = m0 + wr * 64 + mi * 16 + (l >> 4) * 4 + q;
        C[(size_t)row * N + col] = acc[mi][ni][q] + bv;
      }
    }
  }
}

// ---------------- merged QKV + pos GEMM ----------------
__global__ __launch_bounds__(256, 2)
void gemm_qkvpos_kernel(const ushort_t* __restrict__ x_bf, const ushort_t* __restrict__ in_w_bf,
                        const float* __restrict__ in_b,
                        const float* __restrict__ rwb, const float* __restrict__ rrb,
                        const ushort_t* __restrict__ posx_bf, const ushort_t* __restrict__ pos_w_bf,
                        const float* __restrict__ pos_b,
                        ushort_t* __restrict__ qrw, ushort_t* __restrict__ qrr,
                        ushort_t* __restrict__ kbuf, ushort_t* __restrict__ vt,
                        ushort_t* __restrict__ rhp) {
  __shared__ ushort_t As[128 * 32];
  __shared__ ushort_t Bs[128 * 32];
  const int K = 1024;
  const int tid = threadIdx.x;
  const int w = tid >> 6, l = tid & 63;
  const int bid = blockIdx.x;
  const bool isPos = bid >= 768;
  int m0, n0;
  const ushort_t *A, *Bt;
  if (!isPos) {
    m0 = (bid & 31) * 128; n0 = (bid >> 5) * 128; A = x_bf; Bt = in_w_bf;
  } else {
    int pb2 = bid - 768;
    m0 = (pb2 & 7) * 128; n0 = (pb2 >> 3) * 128; A = posx_bf; Bt = pos_w_bf;
  }
  const int wr = w >> 1, wc = w & 1;
  const int fr = l & 15, fk = (l >> 4) * 8;

  f32x4 acc[4][4] = {};

  for (int k0 = 0; k0 < K; k0 += 32) {
    __syncthreads();
#pragma unroll
    for (int p = 0; p < 2; ++p) {
      int c = p * 256 + tid;
      int row = c >> 2, col = (c & 3) * 8;
      GLOAD_LDS16(&A[(size_t)(m0 + row) * K + k0 + col], &As[c * 8]);
      GLOAD_LDS16(&Bt[(size_t)(n0 + row) * K + k0 + col], &Bs[c * 8]);
    }
    __syncthreads();
    short8 af[4], bf[4];
#pragma unroll
    for (int mi = 0; mi < 4; ++mi) af[mi] = *(const short8*)(&As[(wr * 64 + mi * 16 + fr) * 32 + fk]);
#pragma unroll
    for (int ni = 0; ni < 4; ++ni) bf[ni] = *(const short8*)(&Bs[(wc * 64 + ni * 16 + fr) * 32 + fk]);
#pragma unroll
    for (int mi = 0; mi < 4; ++mi)
#pragma unroll
      for (int ni = 0; ni < 4; ++ni)
        acc[mi][ni] = MFMA_BF16(af[mi], bf[ni], acc[mi][ni]);
  }

  if (!isPos) {
#pragma unroll
    for (int ni = 0; ni < 4; ++ni) {
      int col = n0 + wc * 64 + ni * 16 + fr;
      int part = col >> 10;
      int e = col & 1023;
      int hh = e >> 6, dd = e & 63;
      float bv = in_b[col];
      float rwv = rwb[e];
      float rrv = rrb[e];
#pragma unroll
      for (int mi = 0; mi < 4; ++mi) {
#pragma unroll
        for (int q = 0; q < 4; ++q) {
          int row = m0 + wr * 64 + mi * 16 + (l >> 4) * 4 + q;
          int t = row >> 2, b = row & 3;
          float v = acc[mi][ni][q] + bv;
          if (part == 0) {
            unsigned idx = (((unsigned)(b * 16 + hh) * 1024 + t) << 6) + dd;
            qrw[idx] = f2bf(v + rwv);
            qrr[idx] = f2bf(v + rrv);
          } else if (part == 1) {
            unsigned idx = (((unsigned)(b * 16 + hh) * 1024 + t) << 6) + dd;
            kbuf[idx] = f2bf(v);
          } else {
            vt[(((unsigned)(b * 16 + hh) * 64 + dd) << 10) + t] = f2bf(v);
          }
        }
      }
    }
  } else {
#pragma unroll
    for (int ni = 0; ni < 4; ++ni) {
      int col = n0 + wc * 64 + ni * 16 + fr;
      int hh = col >> 6, dd = col & 63;
      float bv = pos_b[col];
#pragma unroll
      for (int mi = 0; mi < 4; ++mi) {
#pragma unroll
        for (int q = 0; q < 4; ++q) {
          int t = m0 + wr * 64 + mi * 16 + (l >> 4) * 4 + q;
          rhp[((unsigned)hh * 1152 + 64 + t) * 64 + dd] = f2bf(acc[mi][ni][q] + bv);
        }
      }
    }
  }
}

// ---------------- attn v7 (R14 restore, setprio removed) ----------------
// R14 was best (202us total). R17 A/B: separate P buffers = neutral-to-negative (the
// serialization is within one strip chain; compiler won't interleave at this reg pressure).
// Single change vs R14: s_setprio removed -- T5 requires wave role diversity (m190: null
// to negative in barrier-lockstep structures like this one).
__global__ __launch_bounds__(256, 2)
void attn_kernel(const ushort_t* __restrict__ qrw, const ushort_t* __restrict__ qrr,
                 const ushort_t* __restrict__ kb, const ushort_t* __restrict__ vt,
                 const ushort_t* __restrict__ rhp, ushort_t* __restrict__ ctx) {
  __shared__ __attribute__((aligned(16))) ushort_t KV[2][8192];  // [buf][K 8KB | V 8KB]
  __shared__ __attribute__((aligned(16))) char PtB[4][2048];     // per-wave P transpose

  const int tid = threadIdx.x, w = tid >> 6, l = tid & 63;
  const int bid = blockIdx.x;
  const int g = bid & 63;
  const int h = ((g & 7) << 1) | ((g >> 3) & 1);   // bid%8 fixes the head-pair (XCD L2 locality)
  const int b = g >> 4;
  const int bh = b * 16 + h;
  const int p = bid >> 6;                          // pair index 0..7
  const int istA = (15 - p) * 64 + w * 16;
  const int istB = p * 64 + w * 16;
  const int njt = 16 - p;
  const int njtB = p + 1;
  const int fr = l & 15, fkq = (l >> 4) * 8;
  const float scale = 0.125f;
  char* Pw = PtB[w];

  short8 aqwA0, aqwA1, aqrA0, aqrA1, aqwB0, aqwB1, aqrB0, aqrB1;
  {
    unsigned qa = ((unsigned)bh * T_LEN + istA + fr) * 64 + fkq;
    aqwA0 = *(const short8*)(qrw + qa);
    aqwA1 = *(const short8*)(qrw + qa + 32);
    aqrA0 = *(const short8*)(qrr + qa);
    aqrA1 = *(const short8*)(qrr + qa + 32);
    unsigned qb = ((unsigned)bh * T_LEN + istB + fr) * 64 + fkq;
    aqwB0 = *(const short8*)(qrw + qb);
    aqwB1 = *(const short8*)(qrw + qb + 32);
    aqrB0 = *(const short8*)(qrr + qb);
    aqrB1 = *(const short8*)(qrr + qb + 32);
  }

  const int srow = 16 * w + (l >> 3);
  const unsigned sswz = (unsigned)(((l & 7) ^ (l >> 3)) << 4);
  const unsigned kgcol = (unsigned)(l & 7) * 8;
  const unsigned swzr = (unsigned)(fr & 7) << 4;

  const unsigned rbaseA = ((unsigned)h * 1152 + 64 + 1008 - istA + fr) * 64 + fkq;
  const unsigned rbaseB = ((unsigned)h * 1152 + 64 + 1008 - istB + fr) * 64 + fkq;

  float sA[4] = {0.f, 0.f, 0.f, 0.f}, sB[4] = {0.f, 0.f, 0.f, 0.f};
  f32x4 oA[4] = {}, oB[4] = {};

  short8 sg0, sg1, sg2, sg3;
#define STAGE_LOAD(J0)                                                              \
  do {                                                                              \
    sg0 = *(const short8*)(kb + ((unsigned)bh * 1024 + (unsigned)(J0) + srow) * 64 + kgcol);      \
    sg1 = *(const short8*)(kb + ((unsigned)bh * 1024 + (unsigned)(J0) + srow + 8) * 64 + kgcol);  \
    sg2 = *(const short8*)(vt + ((unsigned)bh * 64 + srow) * 1024 + (unsigned)(J0) + kgcol);      \
    sg3 = *(const short8*)(vt + ((unsigned)bh * 64 + srow + 8) * 1024 + (unsigned)(J0) + kgcol);  \
  } while (0)
#define STAGE_WRITE(BUF)                                                            \
  do {                                                                              \
    char* KS_ = (char*)KV[BUF];                                                     \
    *(short8*)(KS_ + (unsigned)srow * 128 + sswz) = sg0;                            \
    *(short8*)(KS_ + (unsigned)(srow + 8) * 128 + sswz) = sg1;                      \
    *(short8*)(KS_ + 8192 + (unsigned)srow * 128 + sswz) = sg2;                     \
    *(short8*)(KS_ + 8192 + (unsigned)(srow + 8) * 128 + sswz) = sg3;               \
  } while (0)

#define STRIP_TILE(AQW0, AQW1, AQR0, AQR1, RBASE, IST, SRUN, OACC)                   \
  do {                                                                               \
    short8 rf[10];                                                                   \
    unsigned roff = (RBASE) + (unsigned)j0 * 64;                                     \
    _Pragma("unroll")                                                                \
    for (int f = 0; f < 5; ++f) {                                                    \
      rf[2 * f] = *(const short8*)(rhp + roff + f * 1024);                           \
      rf[2 * f + 1] = *(const short8*)(rhp + roff + f * 1024 + 32);                  \
    }                                                                                \
    f32x4 ac[4] = {};                                                                \
    f32x4 pb[5] = {};                                                                \
    {                                                                                \
      short8 kf[8];                                                                  \
      _Pragma("unroll")                                                              \
      for (int f = 0; f < 4; ++f) {                                                  \
        unsigned rowb = (unsigned)(f * 16 + fr) * 128;                               \
        kf[2 * f] = *(const short8*)(KS + rowb + (((unsigned)fkq * 2) ^ swzr));      \
        kf[2 * f + 1] = *(const short8*)(KS + rowb + (((unsigned)fkq * 2 + 64) ^ swzr)); \
      }                                                                              \
      _Pragma("unroll")                                                              \
      for (int f = 0; f < 4; ++f) {                                                  \
        ac[f] = MFMA_BF16(AQW0, kf[2 * f], ac[f]);                                   \
        ac[f] = MFMA_BF16(AQW1, kf[2 * f + 1], ac[f]);                               \
      }                                                                              \
      _Pragma("unroll")                                                              \
      for (int f = 0; f < 5; ++f) {                                                  \
        pb[f] = MFMA_BF16(AQR0, rf[2 * f], pb[f]);                                   \
        pb[f] = MFMA_BF16(AQR1, rf[2 * f + 1], pb[f]);                               \
      }                                                                              \
    }                                                                                \
    _Pragma("unroll")                                                                \
    for (int q = 0; q < 4; ++q) {                                                    \
      int ri = 4 * (l >> 4) + q;                                                     \
      int e = 15 + fr - ri;                                                          \
      int src = (l & 48) | (e & 15);                                                 \
      float sh[5];                                                                   \
      _Pragma("unroll")                                                              \
      for (int f = 0; f < 5; ++f) sh[f] = __shfl(pb[f][q], src, 64);                 \
      int hi = e >> 4;                                                               \
      int ig = (IST) + ri;                                                           \
      _Pragma("unroll")                                                              \
      for (int ni = 0; ni < 4; ++ni) {                                               \
        float pv = hi ? sh[ni + 1] : sh[ni];                                         \
        float s = (ac[ni][q] + pv) * scale - 20.0f;                                  \
        int jg = j0 + ni * 16 + fr;                                                  \
        float pp = (jg > ig) ? 0.f : __expf(s);                                      \
        *(ushort_t*)(Pw + (((ri * 128) + (ni * 16 + fr) * 2) ^ ((ri & 7) << 4))) = f2bf(pp); \
        SRUN[q] += pp;                                                               \
      }                                                                              \
    }                                                                                \
    {                                                                                \
      short8 vf[8];                                                                  \
      _Pragma("unroll")                                                              \
      for (int dg = 0; dg < 4; ++dg) {                                               \
        unsigned rowb = 8192 + (unsigned)(dg * 16 + fr) * 128;                       \
        vf[2 * dg] = *(const short8*)(KS + rowb + (((unsigned)fkq * 2) ^ swzr));     \
        vf[2 * dg + 1] = *(const short8*)(KS + rowb + (((unsigned)(64 + fkq * 2)) ^ swzr)); \
      }                                                                              \
      short8 pa0 = *(const short8*)(Pw + ((fr * 128 + fkq * 2) ^ ((fr & 7) << 4)));  \
      short8 pa1 = *(const short8*)(Pw + ((fr * 128 + 64 + fkq * 2) ^ ((fr & 7) << 4))); \
      _Pragma("unroll")                                                              \
      for (int dg = 0; dg < 4; ++dg) {                                               \
        OACC[dg] = MFMA_BF16(pa0, vf[2 * dg], OACC[dg]);                             \
        OACC[dg] = MFMA_BF16(pa1, vf[2 * dg + 1], OACC[dg]);                         \
      }                                                                              \
    }                                                                                \
  } while (0)

  // prologue: stage tile 0
  STAGE_LOAD(0);
  STAGE_WRITE(0);
  __syncthreads();

  for (int jt = 0; jt < njt; ++jt) {
    const int j0 = jt << 6;
    const char* KS = (const char*)KV[jt & 1];

    if (jt + 1 < njt) STAGE_LOAD((jt + 1) << 6);

    STRIP_TILE(aqwA0, aqwA1, aqrA0, aqrA1, rbaseA, istA, sA, oA);
    if (jt < njtB) STRIP_TILE(aqwB0, aqwB1, aqrB0, aqrB1, rbaseB, istB, sB, oB);

    if (jt + 1 < njt) STAGE_WRITE((jt + 1) & 1);
    __syncthreads();
  }

  // ---- epilogue ----
#pragma unroll
  for (int q = 0; q < 4; ++q) {
    float a = sA[q], bq = sB[q];
#pragma unroll
    for (int o2 = 8; o2; o2 >>= 1) {
      a += __shfl_xor(a, o2, 64);
      bq += __shfl_xor(bq, o2, 64);
    }
    sA[q] = a;
    sB[q] = bq;
  }
#pragma unroll
  for (int dg = 0; dg < 4; ++dg) {
#pragma unroll
    for (int q = 0; q < 4; ++q) {
      int dd = dg * 16 + fr;
      int igA = istA + 4 * (l >> 4) + q;
      ctx[((size_t)igA * BATCH + b) * EMB + h * 64 + dd] = f2bf(oA[dg][q] / sA[q]);
      int igB = istB + 4 * (l >> 4) + q;
      ctx[((size_t)igB * BATCH + b) * EMB + h * 64 + dd] = f2bf(oB[dg][q] / sB[q]);
    }
  }
}

// ---------------- launch ----------------
extern "C" void kernel_launch(void* const* d_in, const int* in_sizes, int n_in,
                              void* d_out, int out_size, void* d_ws, size_t ws_size,
                              hipStream_t stream) {
  (void)in_sizes; (void)n_in; (void)out_size; (void)ws_size;
  const float* x = (const float*)d_in[0];
  const float* pos = (const float*)d_in[1];
  const float* in_w_mu = (const float*)d_in[3];
  const float* in_w_rho = (const float*)d_in[4];
  const float* in_w_eps = (const float*)d_in[5];
  const float* in_b_mu = (const float*)d_in[6];
  const float* in_b_rho = (const float*)d_in[7];
  const float* in_b_eps = (const float*)d_in[8];
  const float* pos_w_mu = (const float*)d_in[9];
  const float* pos_w_rho = (const float*)d_in[10];
  const float* pos_w_eps = (const float*)d_in[11];
  const float* pos_b_mu = (const float*)d_in[12];
  const float* pos_b_rho = (const float*)d_in[13];
  const float* pos_b_eps = (const float*)d_in[14];
  const float* out_w_mu = (const float*)d_in[15];
  const float* out_w_rho = (const float*)d_in[16];
  const float* out_w_eps = (const float*)d_in[17];
  const float* out_b_mu = (const float*)d_in[18];
  const float* out_b_rho = (const float*)d_in[19];
  const float* out_b_eps = (const float*)d_in[20];
  const float* rw_mu = (const float*)d_in[21];
  const float* rw_rho = (const float*)d_in[22];
  const float* rw_eps = (const float*)d_in[23];
  const float* rr_mu = (const float*)d_in[24];
  const float* rr_rho = (const float*)d_in[25];
  const float* rr_eps = (const float*)d_in[26];

  char* ws = (char*)d_ws;
  ushort_t* in_w_bf  = (ushort_t*)(ws + 0);
  ushort_t* pos_w_bf = (ushort_t*)(ws + 6291456);
  ushort_t* out_w_bf = (ushort_t*)(ws + 8388608);
  float* in_b  = (float*)(ws + 10485760);
  float* pos_b = (float*)(ws + 10498048);
  float* out_b = (float*)(ws + 10502144);
  float* rwb   = (float*)(ws + 10506240);
  float* rrb   = (float*)(ws + 10510336);
  ushort_t* x_bf    = (ushort_t*)(ws + 10514432);
  ushort_t* posx_bf = (ushort_t*)(ws + 18903040);
  ushort_t* qrw = (ushort_t*)(ws + 21000192);
  ushort_t* qrr = (ushort_t*)(ws + 29388800);
  ushort_t* kb  = (ushort_t*)(ws + 37777408);
  ushort_t* vt  = (ushort_t*)(ws + 46166016);
  ushort_t* rhp = (ushort_t*)(ws + 54554624);
  ushort_t* ctx = (ushort_t*)(ws + 56913920);

  sample_w_kernel<<<5120, 256, 0, stream>>>(in_w_mu, in_w_rho, in_w_eps, in_w_bf,
                                            pos_w_mu, pos_w_rho, pos_w_eps, pos_w_bf,
                                            out_w_mu, out_w_rho, out_w_eps, out_w_bf);
  sample_bias_kernel<<<28, 256, 0, stream>>>(in_b_mu, in_b_rho, in_b_eps, in_b,
                                             pos_b_mu, pos_b_rho, pos_b_eps, pos_b,
                                             out_b_mu, out_b_rho, out_b_eps, out_b,
                                             rw_mu, rw_rho, rw_eps, rwb,
                                             rr_mu, rr_rho, rr_eps, rrb);
  cast_bf16x4_kernel<<<4096, 256, 0, stream>>>(x, x_bf, 1048576);
  cast_bf16x4_kernel<<<1024, 256, 0, stream>>>(pos, posx_bf, 262144);
  zero_rhp_pad_kernel<<<512, 256, 0, stream>>>(rhp);

  gemm_qkvpos_kernel<<<832, 256, 0, stream>>>(x_bf, in_w_bf, in_b, rwb, rrb,
                                              posx_bf, pos_w_bf, pos_b,
                                              qrw, qrr, kb, vt, rhp);

  attn_kernel<<<dim3(512), 256, 0, stream>>>(qrw, qrr, kb, vt, rhp, ctx);

  gemm_bt_kernel<<<dim3(32, 8), 256, 0, stream>>>(ctx, out_w_bf, out_b, (float*)d_out, 4096, 1024, 1024);
}

// Round 19
// 169.924 us; speedup vs baseline: 2.3836x; 1.1937x over previous
//
#include <hip/hip_runtime.h>

typedef unsigned short ushort_t;
typedef __attribute__((ext_vector_type(8))) short short8;
typedef __attribute__((ext_vector_type(4))) float f32x4;
typedef __attribute__((ext_vector_type(4))) unsigned short ush4;

#define MFMA_BF16(a, b, c) __builtin_amdgcn_mfma_f32_16x16x32_bf16((a), (b), (c), 0, 0, 0)

#define GLOAD_LDS16(GP, LP)                                                       \
  __builtin_amdgcn_global_load_lds(                                               \
      (const __attribute__((address_space(1))) void*)(GP),                        \
      (__attribute__((address_space(3))) void*)(LP), 16, 0, 0)

#define T_LEN 1024
#define BATCH 4
#define NHEAD 16
#define DHEAD 64
#define EMB 1024

__device__ __forceinline__ ushort_t f2bf(float f) {
  unsigned u = __float_as_uint(f);
  u += 0x7fffu + ((u >> 16) & 1u);
  return (ushort_t)(u >> 16);
}

// ---------------- elementwise ----------------
__global__ void sample_w_kernel(const float* __restrict__ im, const float* __restrict__ ir,
                                const float* __restrict__ ie, ushort_t* __restrict__ io,
                                const float* __restrict__ pm, const float* __restrict__ pr,
                                const float* __restrict__ pe, ushort_t* __restrict__ po,
                                const float* __restrict__ om, const float* __restrict__ orh,
                                const float* __restrict__ oe, ushort_t* __restrict__ oo) {
  int i = blockIdx.x * 256 + threadIdx.x;
  const float *mu, *rho, *eps;
  ushort_t* out;
  int j;
  if (i < 786432) { mu = im; rho = ir; eps = ie; out = io; j = i; }
  else if (i < 1048576) { mu = pm; rho = pr; eps = pe; out = po; j = i - 786432; }
  else { mu = om; rho = orh; eps = oe; out = oo; j = i - 1048576; }
  f32x4 m = *(const f32x4*)(mu + (size_t)j * 4);
  f32x4 r = *(const f32x4*)(rho + (size_t)j * 4);
  f32x4 e = *(const f32x4*)(eps + (size_t)j * 4);
  ush4 o;
#pragma unroll
  for (int k = 0; k < 4; ++k) o[k] = f2bf(m[k] + log1pf(__expf(r[k])) * e[k]);
  *(ush4*)(out + (size_t)j * 4) = o;
}

__global__ void sample_bias_kernel(
    const float* __restrict__ am, const float* __restrict__ ar, const float* __restrict__ ae, float* __restrict__ ao,
    const float* __restrict__ bm, const float* __restrict__ br, const float* __restrict__ be, float* __restrict__ bo,
    const float* __restrict__ cm, const float* __restrict__ cr, const float* __restrict__ ce, float* __restrict__ co,
    const float* __restrict__ dm, const float* __restrict__ dr, const float* __restrict__ de, float* __restrict__ dof,
    const float* __restrict__ em, const float* __restrict__ er, const float* __restrict__ ee, float* __restrict__ eo) {
  int i = blockIdx.x * 256 + threadIdx.x;
  if (i < 3072) {
    ao[i] = am[i] + log1pf(__expf(ar[i])) * ae[i];
  } else if (i < 4096) {
    int j = i - 3072; bo[j] = bm[j] + log1pf(__expf(br[j])) * be[j];
  } else if (i < 5120) {
    int j = i - 4096; co[j] = cm[j] + log1pf(__expf(cr[j])) * ce[j];
  } else if (i < 6144) {
    int j = i - 5120; dof[j] = dm[j] + log1pf(__expf(dr[j])) * de[j];
  } else if (i < 7168) {
    int j = i - 6144; eo[j] = em[j] + log1pf(__expf(er[j])) * ee[j];
  }
}

__global__ void cast_bf16x4_kernel(const float* __restrict__ in, ushort_t* __restrict__ out, int n4) {
  int i = blockIdx.x * 256 + threadIdx.x;
  if (i < n4) {
    f32x4 v = *(const f32x4*)(in + (size_t)i * 4);
    ush4 o;
#pragma unroll
    for (int j = 0; j < 4; ++j) o[j] = f2bf(v[j]);
    *(ush4*)(out + (size_t)i * 4) = o;
  }
}

__global__ void zero_rhp_pad_kernel(ushort_t* __restrict__ rhp) {
  int idx = blockIdx.x * 256 + threadIdx.x;
  int dd = idx & 63;
  int pr = (idx >> 6) & 127;
  int h = idx >> 13;
  int phys = (pr < 64) ? pr : (pr - 64 + 1088);
  rhp[((size_t)h * 1152 + phys) * 64 + dd] = 0;
}

// ---------------- GEMM (out-proj) ----------------
__global__ __launch_bounds__(256, 2)
void gemm_bt_kernel(const ushort_t* __restrict__ A, const ushort_t* __restrict__ Bt,
                    const float* __restrict__ bias, float* __restrict__ C,
                    int M, int N, int K) {
  __shared__ ushort_t As[128 * 32];
  __shared__ ushort_t Bs[128 * 32];
  const int tid = threadIdx.x;
  const int w = tid >> 6, l = tid & 63;
  const int m0 = blockIdx.x * 128, n0 = blockIdx.y * 128;
  const int wr = w >> 1, wc = w & 1;
  const int fr = l & 15, fk = (l >> 4) * 8;

  f32x4 acc[4][4] = {};

  for (int k0 = 0; k0 < K; k0 += 32) {
    __syncthreads();
#pragma unroll
    for (int p = 0; p < 2; ++p) {
      int c = p * 256 + tid;
      int row = c >> 2, col = (c & 3) * 8;
      GLOAD_LDS16(&A[(size_t)(m0 + row) * K + k0 + col], &As[c * 8]);
      GLOAD_LDS16(&Bt[(size_t)(n0 + row) * K + k0 + col], &Bs[c * 8]);
    }
    __syncthreads();
    short8 af[4], bf[4];
#pragma unroll
    for (int mi = 0; mi < 4; ++mi) af[mi] = *(const short8*)(&As[(wr * 64 + mi * 16 + fr) * 32 + fk]);
#pragma unroll
    for (int ni = 0; ni < 4; ++ni) bf[ni] = *(const short8*)(&Bs[(wc * 64 + ni * 16 + fr) * 32 + fk]);
#pragma unroll
    for (int mi = 0; mi < 4; ++mi)
#pragma unroll
      for (int ni = 0; ni < 4; ++ni)
        acc[mi][ni] = MFMA_BF16(af[mi], bf[ni], acc[mi][ni]);
  }

#pragma unroll
  for (int ni = 0; ni < 4; ++ni) {
    int col = n0 + wc * 64 + ni * 16 + fr;
    float bv = bias[col];
#pragma unroll
    for (int mi = 0; mi < 4; ++mi) {
#pragma unroll
      for (int q = 0; q < 4; ++q) {
        int row = m0 + wr * 64 + mi * 16 + (l >> 4) * 4 + q;
        C[(size_t)row * N + col] = acc[mi][ni][q] + bv;
      }
    }
  }
}

// ---------------- merged QKV + pos GEMM ----------------
__global__ __launch_bounds__(256, 2)
void gemm_qkvpos_kernel(const ushort_t* __restrict__ x_bf, const ushort_t* __restrict__ in_w_bf,
                        const float* __restrict__ in_b,
                        const float* __restrict__ rwb, const float* __restrict__ rrb,
                        const ushort_t* __restrict__ posx_bf, const ushort_t* __restrict__ pos_w_bf,
                        const float* __restrict__ pos_b,
                        ushort_t* __restrict__ qrw, ushort_t* __restrict__ qrr,
                        ushort_t* __restrict__ kbuf, ushort_t* __restrict__ vt,
                        ushort_t* __restrict__ rhp) {
  __shared__ ushort_t As[128 * 32];
  __shared__ ushort_t Bs[128 * 32];
  const int K = 1024;
  const int tid = threadIdx.x;
  const int w = tid >> 6, l = tid & 63;
  const int bid = blockIdx.x;
  const bool isPos = bid >= 768;
  int m0, n0;
  const ushort_t *A, *Bt;
  if (!isPos) {
    m0 = (bid & 31) * 128; n0 = (bid >> 5) * 128; A = x_bf; Bt = in_w_bf;
  } else {
    int pb2 = bid - 768;
    m0 = (pb2 & 7) * 128; n0 = (pb2 >> 3) * 128; A = posx_bf; Bt = pos_w_bf;
  }
  const int wr = w >> 1, wc = w & 1;
  const int fr = l & 15, fk = (l >> 4) * 8;

  f32x4 acc[4][4] = {};

  for (int k0 = 0; k0 < K; k0 += 32) {
    __syncthreads();
#pragma unroll
    for (int p = 0; p < 2; ++p) {
      int c = p * 256 + tid;
      int row = c >> 2, col = (c & 3) * 8;
      GLOAD_LDS16(&A[(size_t)(m0 + row) * K + k0 + col], &As[c * 8]);
      GLOAD_LDS16(&Bt[(size_t)(n0 + row) * K + k0 + col], &Bs[c * 8]);
    }
    __syncthreads();
    short8 af[4], bf[4];
#pragma unroll
    for (int mi = 0; mi < 4; ++mi) af[mi] = *(const short8*)(&As[(wr * 64 + mi * 16 + fr) * 32 + fk]);
#pragma unroll
    for (int ni = 0; ni < 4; ++ni) bf[ni] = *(const short8*)(&Bs[(wc * 64 + ni * 16 + fr) * 32 + fk]);
#pragma unroll
    for (int mi = 0; mi < 4; ++mi)
#pragma unroll
      for (int ni = 0; ni < 4; ++ni)
        acc[mi][ni] = MFMA_BF16(af[mi], bf[ni], acc[mi][ni]);
  }

  if (!isPos) {
#pragma unroll
    for (int ni = 0; ni < 4; ++ni) {
      int col = n0 + wc * 64 + ni * 16 + fr;
      int part = col >> 10;
      int e = col & 1023;
      int hh = e >> 6, dd = e & 63;
      float bv = in_b[col];
      float rwv = rwb[e];
      float rrv = rrb[e];
#pragma unroll
      for (int mi = 0; mi < 4; ++mi) {
#pragma unroll
        for (int q = 0; q < 4; ++q) {
          int row = m0 + wr * 64 + mi * 16 + (l >> 4) * 4 + q;
          int t = row >> 2, b = row & 3;
          float v = acc[mi][ni][q] + bv;
          if (part == 0) {
            unsigned idx = (((unsigned)(b * 16 + hh) * 1024 + t) << 6) + dd;
            qrw[idx] = f2bf(v + rwv);
            qrr[idx] = f2bf(v + rrv);
          } else if (part == 1) {
            unsigned idx = (((unsigned)(b * 16 + hh) * 1024 + t) << 6) + dd;
            kbuf[idx] = f2bf(v);
          } else {
            vt[(((unsigned)(b * 16 + hh) * 64 + dd) << 10) + t] = f2bf(v);
          }
        }
      }
    }
  } else {
#pragma unroll
    for (int ni = 0; ni < 4; ++ni) {
      int col = n0 + wc * 64 + ni * 16 + fr;
      int hh = col >> 6, dd = col & 63;
      float bv = pos_b[col];
#pragma unroll
      for (int mi = 0; mi < 4; ++mi) {
#pragma unroll
        for (int q = 0; q < 4; ++q) {
          int t = m0 + wr * 64 + mi * 16 + (l >> 4) * 4 + q;
          rhp[((unsigned)hh * 1152 + 64 + t) * 64 + dd] = f2bf(acc[mi][ni][q] + bv);
        }
      }
    }
  }
}

// ---------------- attn v9: single-strip, 32-col tiles, gload_lds staging ----------------
// Goal: unified regs <= 128 -> 4 waves/SIMD (the 129-256 bucket at 2 waves/SIMD has been
// the plateau since R11). Cuts: single strip (halves persistent state), 32-col K-tiles
// (smaller transients: rf 6, kf 4, pb 3, ac 2), K/V staged by global_load_lds with
// pre-swizzled GLOBAL source chunks (linear LDS dest; XOR involution on read) -> zero
// staging registers. Static-max softmax; per-wave causal skip; block-uniform staging.
__global__ __launch_bounds__(256, 2)
void attn_kernel(const ushort_t* __restrict__ qrw, const ushort_t* __restrict__ qrr,
                 const ushort_t* __restrict__ kb, const ushort_t* __restrict__ vt,
                 const ushort_t* __restrict__ rhp, ushort_t* __restrict__ ctx) {
  __shared__ __attribute__((aligned(16))) ushort_t KV[2][4096];  // per buf: K[32][64] | V[64][32], 8KB
  __shared__ __attribute__((aligned(16))) char PtB[4][1024];     // per wave: P[16][32] bf16, chunk-swizzled

  const int tid = threadIdx.x, w = tid >> 6, l = tid & 63;
  const int bid = blockIdx.x;
  const int g = bid & 63;
  const int h = ((g & 7) << 1) | ((g >> 3) & 1);   // bid%8 -> head-pair (XCD L2 locality)
  const int b = g >> 4;
  const int bh = b * 16 + h;
  const int sx = 15 - (bid >> 6);                  // reversed: big strips first
  const int istrip = sx * 64 + w * 16;
  const int fr = l & 15, fkq = (l >> 4) * 8;
  const float scale = 0.125f;
  char* Pw = PtB[w];
  const int njt = (sx + 1) * 2;                    // 32-col tiles, block-uniform
  const int jlim = istrip + 15;                    // wave compute bound
  const unsigned swzr = (unsigned)(fr & 7) << 4;   // K read swizzle (rows fr, 16+fr share &7)
  const unsigned swzp = (unsigned)((fr >> 1) & 3) << 4;  // P/V read swizzle helper (row=...+fr)

  // Q fragments
  short8 aqw0, aqw1, aqr0, aqr1;
  {
    unsigned qb = ((unsigned)bh * T_LEN + istrip + fr) * 64 + fkq;
    aqw0 = *(const short8*)(qrw + qb);
    aqw1 = *(const short8*)(qrw + qb + 32);
    aqr0 = *(const short8*)(qrr + qb);
    aqr1 = *(const short8*)(qrr + qb + 32);
  }

  // staging source addressing (pre-swizzled global chunk index; LDS dest linear in tid)
  const int krow = tid >> 3;                                   // 0..31
  const int kci8 = ((tid & 7) ^ (krow & 7)) * 8;               // global d-chunk, pre-swizzled
  const int vdr = tid >> 2;                                    // 0..63
  const int vci8 = ((tid & 3) ^ ((vdr >> 1) & 3)) * 8;         // global t-chunk, pre-swizzled
  const ushort_t* kgbase = kb + ((unsigned)bh * 1024 + krow) * 64 + kci8;
  const ushort_t* vgbase = vt + ((unsigned)bh * 64 + vdr) * 1024 + vci8;

  const unsigned rbase = ((unsigned)h * 1152 + 64 + 1008 - istrip + fr) * 64 + fkq;

  float s_run[4] = {0.f, 0.f, 0.f, 0.f};
  f32x4 o[4] = {};

#define STAGE(J0, BUF)                                                    \
  do {                                                                    \
    ushort_t* Kd = (ushort_t*)KV[BUF];                                    \
    GLOAD_LDS16(kgbase + (unsigned)(J0) * 64, Kd + tid * 8);              \
    GLOAD_LDS16(vgbase + (unsigned)(J0), Kd + 2048 + tid * 8);            \
  } while (0)

  // prologue
  STAGE(0, 0);
  __syncthreads();

  for (int jt = 0; jt < njt; ++jt) {
    const int j0 = jt << 5;
    const int buf = jt & 1;
    if (jt + 1 < njt) STAGE((jt + 1) << 5, buf ^ 1);

    if (j0 <= jlim) {
      const char* KS = (const char*)KV[buf];

      // R band loads (global, 3 frags x 2 halves)
      short8 rf[6];
      {
        unsigned roff = rbase + (unsigned)j0 * 64;
#pragma unroll
        for (int f = 0; f < 3; ++f) {
          rf[2 * f] = *(const short8*)(rhp + roff + f * 1024);
          rf[2 * f + 1] = *(const short8*)(rhp + roff + f * 1024 + 32);
        }
      }
      // K fragments from LDS (2 col-frags x 2 K-halves)
      f32x4 ac0 = {0, 0, 0, 0}, ac1 = {0, 0, 0, 0};
      f32x4 pb0 = {0, 0, 0, 0}, pb1 = {0, 0, 0, 0}, pb2 = {0, 0, 0, 0};
      {
        short8 kf00 = *(const short8*)(KS + (unsigned)fr * 128 + (((unsigned)fkq * 2) ^ swzr));
        short8 kf01 = *(const short8*)(KS + (unsigned)fr * 128 + (((unsigned)(64 + fkq * 2)) ^ swzr));
        short8 kf10 = *(const short8*)(KS + (unsigned)(16 + fr) * 128 + (((unsigned)fkq * 2) ^ swzr));
        short8 kf11 = *(const short8*)(KS + (unsigned)(16 + fr) * 128 + (((unsigned)(64 + fkq * 2)) ^ swzr));
        ac0 = MFMA_BF16(aqw0, kf00, ac0);
        ac0 = MFMA_BF16(aqw1, kf01, ac0);
        ac1 = MFMA_BF16(aqw0, kf10, ac1);
        ac1 = MFMA_BF16(aqw1, kf11, ac1);
      }
      pb0 = MFMA_BF16(aqr0, rf[0], pb0);
      pb0 = MFMA_BF16(aqr1, rf[1], pb0);
      pb1 = MFMA_BF16(aqr0, rf[2], pb1);
      pb1 = MFMA_BF16(aqr1, rf[3], pb1);
      pb2 = MFMA_BF16(aqr0, rf[4], pb2);
      pb2 = MFMA_BF16(aqr1, rf[5], pb2);

      // rel-shift gather + static-max softmax -> P (chunk-swizzled)
#pragma unroll
      for (int q = 0; q < 4; ++q) {
        int ri = 4 * (l >> 4) + q;
        int e = 15 + fr - ri;                       // in [0,30]
        int src = (l & 48) | (e & 15);
        float sh0 = __shfl(pb0[q], src, 64);
        float sh1 = __shfl(pb1[q], src, 64);
        float sh2 = __shfl(pb2[q], src, 64);
        int hi = e >> 4;
        float pv0 = hi ? sh1 : sh0;
        float pv1 = hi ? sh2 : sh1;
        int ig = istrip + ri;
        float s0 = (ac0[q] + pv0) * scale - 20.0f;
        float s1 = (ac1[q] + pv1) * scale - 20.0f;
        float p0 = (j0 + fr > ig) ? 0.f : __expf(s0);
        float p1 = (j0 + 16 + fr > ig) ? 0.f : __expf(s1);
        unsigned psw = (unsigned)((ri >> 1) & 3) << 4;
        *(ushort_t*)(Pw + ri * 64 + (((unsigned)(fr * 2)) ^ psw)) = f2bf(p0);
        *(ushort_t*)(Pw + ri * 64 + (((unsigned)(32 + fr * 2)) ^ psw)) = f2bf(p1);
        s_run[q] += p0 + p1;
      }

      // PV (K=32: one MFMA per d-group)
      {
        short8 pa = *(const short8*)(Pw + (unsigned)fr * 64 + (((unsigned)fkq * 2) ^ swzp));
#pragma unroll
        for (int dg = 0; dg < 4; ++dg) {
          int vrow = dg * 16 + fr;
          short8 vf = *(const short8*)(KS + 4096 + (unsigned)vrow * 64 +
                                       (((unsigned)fkq * 2) ^ ((unsigned)((vrow >> 1) & 3) << 4)));
          o[dg] = MFMA_BF16(pa, vf, o[dg]);
        }
      }
    }

    __syncthreads();
  }

  // epilogue: row-sum reduce (within fr group), normalize, write ctx
#pragma unroll
  for (int q = 0; q < 4; ++q) {
    float sq = s_run[q];
#pragma unroll
    for (int o2 = 8; o2; o2 >>= 1) sq += __shfl_xor(sq, o2, 64);
    s_run[q] = sq;
  }
#pragma unroll
  for (int dg = 0; dg < 4; ++dg) {
#pragma unroll
    for (int q = 0; q < 4; ++q) {
      int ig = istrip + 4 * (l >> 4) + q;
      int dd = dg * 16 + fr;
      ctx[((size_t)ig * BATCH + b) * EMB + h * 64 + dd] = f2bf(o[dg][q] / s_run[q]);
    }
  }
}

// ---------------- launch ----------------
extern "C" void kernel_launch(void* const* d_in, const int* in_sizes, int n_in,
                              void* d_out, int out_size, void* d_ws, size_t ws_size,
                              hipStream_t stream) {
  (void)in_sizes; (void)n_in; (void)out_size; (void)ws_size;
  const float* x = (const float*)d_in[0];
  const float* pos = (const float*)d_in[1];
  const float* in_w_mu = (const float*)d_in[3];
  const float* in_w_rho = (const float*)d_in[4];
  const float* in_w_eps = (const float*)d_in[5];
  const float* in_b_mu = (const float*)d_in[6];
  const float* in_b_rho = (const float*)d_in[7];
  const float* in_b_eps = (const float*)d_in[8];
  const float* pos_w_mu = (const float*)d_in[9];
  const float* pos_w_rho = (const float*)d_in[10];
  const float* pos_w_eps = (const float*)d_in[11];
  const float* pos_b_mu = (const float*)d_in[12];
  const float* pos_b_rho = (const float*)d_in[13];
  const float* pos_b_eps = (const float*)d_in[14];
  const float* out_w_mu = (const float*)d_in[15];
  const float* out_w_rho = (const float*)d_in[16];
  const float* out_w_eps = (const float*)d_in[17];
  const float* out_b_mu = (const float*)d_in[18];
  const float* out_b_rho = (const float*)d_in[19];
  const float* out_b_eps = (const float*)d_in[20];
  const float* rw_mu = (const float*)d_in[21];
  const float* rw_rho = (const float*)d_in[22];
  const float* rw_eps = (const float*)d_in[23];
  const float* rr_mu = (const float*)d_in[24];
  const float* rr_rho = (const float*)d_in[25];
  const float* rr_eps = (const float*)d_in[26];

  char* ws = (char*)d_ws;
  ushort_t* in_w_bf  = (ushort_t*)(ws + 0);
  ushort_t* pos_w_bf = (ushort_t*)(ws + 6291456);
  ushort_t* out_w_bf = (ushort_t*)(ws + 8388608);
  float* in_b  = (float*)(ws + 10485760);
  float* pos_b = (float*)(ws + 10498048);
  float* out_b = (float*)(ws + 10502144);
  float* rwb   = (float*)(ws + 10506240);
  float* rrb   = (float*)(ws + 10510336);
  ushort_t* x_bf    = (ushort_t*)(ws + 10514432);
  ushort_t* posx_bf = (ushort_t*)(ws + 18903040);
  ushort_t* qrw = (ushort_t*)(ws + 21000192);
  ushort_t* qrr = (ushort_t*)(ws + 29388800);
  ushort_t* kb  = (ushort_t*)(ws + 37777408);
  ushort_t* vt  = (ushort_t*)(ws + 46166016);
  ushort_t* rhp = (ushort_t*)(ws + 54554624);
  ushort_t* ctx = (ushort_t*)(ws + 56913920);

  sample_w_kernel<<<5120, 256, 0, stream>>>(in_w_mu, in_w_rho, in_w_eps, in_w_bf,
                                            pos_w_mu, pos_w_rho, pos_w_eps, pos_w_bf,
                                            out_w_mu, out_w_rho, out_w_eps, out_w_bf);
  sample_bias_kernel<<<28, 256, 0, stream>>>(in_b_mu, in_b_rho, in_b_eps, in_b,
                                             pos_b_mu, pos_b_rho, pos_b_eps, pos_b,
                                             out_b_mu, out_b_rho, out_b_eps, out_b,
                                             rw_mu, rw_rho, rw_eps, rwb,
                                             rr_mu, rr_rho, rr_eps, rrb);
  cast_bf16x4_kernel<<<4096, 256, 0, stream>>>(x, x_bf, 1048576);
  cast_bf16x4_kernel<<<1024, 256, 0, stream>>>(pos, posx_bf, 262144);
  zero_rhp_pad_kernel<<<512, 256, 0, stream>>>(rhp);

  gemm_qkvpos_kernel<<<832, 256, 0, stream>>>(x_bf, in_w_bf, in_b, rwb, rrb,
                                              posx_bf, pos_w_bf, pos_b,
                                              qrw, qrr, kb, vt, rhp);

  attn_kernel<<<dim3(1024), 256, 0, stream>>>(qrw, qrr, kb, vt, rhp, ctx);

  gemm_bt_kernel<<<dim3(32, 8), 256, 0, stream>>>(ctx, out_w_bf, out_b, (float*)d_out, 4096, 1024, 1024);
}

// Round 20
// 169.810 us; speedup vs baseline: 2.3852x; 1.0007x over previous
//
#include <hip/hip_runtime.h>

typedef unsigned short ushort_t;
typedef __attribute__((ext_vector_type(8))) short short8;
typedef __attribute__((ext_vector_type(4))) float f32x4;
typedef __attribute__((ext_vector_type(4))) unsigned short ush4;

#define MFMA_BF16(a, b, c) __builtin_amdgcn_mfma_f32_16x16x32_bf16((a), (b), (c), 0, 0, 0)

#define GLOAD_LDS16(GP, LP)                                                       \
  __builtin_amdgcn_global_load_lds(                                               \
      (const __attribute__((address_space(1))) void*)(GP),                        \
      (__attribute__((address_space(3))) void*)(LP), 16, 0, 0)

#define T_LEN 1024
#define BATCH 4
#define NHEAD 16
#define DHEAD 64
#define EMB 1024

__device__ __forceinline__ ushort_t f2bf(float f) {
  unsigned u = __float_as_uint(f);
  u += 0x7fffu + ((u >> 16) & 1u);
  return (ushort_t)(u >> 16);
}

// ---------------- elementwise ----------------
__global__ void sample_w_kernel(const float* __restrict__ im, const float* __restrict__ ir,
                                const float* __restrict__ ie, ushort_t* __restrict__ io,
                                const float* __restrict__ pm, const float* __restrict__ pr,
                                const float* __restrict__ pe, ushort_t* __restrict__ po,
                                const float* __restrict__ om, const float* __restrict__ orh,
                                const float* __restrict__ oe, ushort_t* __restrict__ oo) {
  int i = blockIdx.x * 256 + threadIdx.x;
  const float *mu, *rho, *eps;
  ushort_t* out;
  int j;
  if (i < 786432) { mu = im; rho = ir; eps = ie; out = io; j = i; }
  else if (i < 1048576) { mu = pm; rho = pr; eps = pe; out = po; j = i - 786432; }
  else { mu = om; rho = orh; eps = oe; out = oo; j = i - 1048576; }
  f32x4 m = *(const f32x4*)(mu + (size_t)j * 4);
  f32x4 r = *(const f32x4*)(rho + (size_t)j * 4);
  f32x4 e = *(const f32x4*)(eps + (size_t)j * 4);
  ush4 o;
#pragma unroll
  for (int k = 0; k < 4; ++k) o[k] = f2bf(m[k] + log1pf(__expf(r[k])) * e[k]);
  *(ush4*)(out + (size_t)j * 4) = o;
}

__global__ void sample_bias_kernel(
    const float* __restrict__ am, const float* __restrict__ ar, const float* __restrict__ ae, float* __restrict__ ao,
    const float* __restrict__ bm, const float* __restrict__ br, const float* __restrict__ be, float* __restrict__ bo,
    const float* __restrict__ cm, const float* __restrict__ cr, const float* __restrict__ ce, float* __restrict__ co,
    const float* __restrict__ dm, const float* __restrict__ dr, const float* __restrict__ de, float* __restrict__ dof,
    const float* __restrict__ em, const float* __restrict__ er, const float* __restrict__ ee, float* __restrict__ eo) {
  int i = blockIdx.x * 256 + threadIdx.x;
  if (i < 3072) {
    ao[i] = am[i] + log1pf(__expf(ar[i])) * ae[i];
  } else if (i < 4096) {
    int j = i - 3072; bo[j] = bm[j] + log1pf(__expf(br[j])) * be[j];
  } else if (i < 5120) {
    int j = i - 4096; co[j] = cm[j] + log1pf(__expf(cr[j])) * ce[j];
  } else if (i < 6144) {
    int j = i - 5120; dof[j] = dm[j] + log1pf(__expf(dr[j])) * de[j];
  } else if (i < 7168) {
    int j = i - 6144; eo[j] = em[j] + log1pf(__expf(er[j])) * ee[j];
  }
}

__global__ void cast_bf16x4_kernel(const float* __restrict__ in, ushort_t* __restrict__ out, int n4) {
  int i = blockIdx.x * 256 + threadIdx.x;
  if (i < n4) {
    f32x4 v = *(const f32x4*)(in + (size_t)i * 4);
    ush4 o;
#pragma unroll
    for (int j = 0; j < 4; ++j) o[j] = f2bf(v[j]);
    *(ush4*)(out + (size_t)i * 4) = o;
  }
}

__global__ void zero_rhp_pad_kernel(ushort_t* __restrict__ rhp) {
  int idx = blockIdx.x * 256 + threadIdx.x;
  int dd = idx & 63;
  int pr = (idx >> 6) & 127;
  int h = idx >> 13;
  int phys = (pr < 64) ? pr : (pr - 64 + 1088);
  rhp[((size_t)h * 1152 + phys) * 64 + dd] = 0;
}

// ---------------- GEMM (out-proj): (256,4) -> 124 unified regs fit 128 budget, 4 blk/CU ----
__global__ __launch_bounds__(256, 4)
void gemm_bt_kernel(const ushort_t* __restrict__ A, const ushort_t* __restrict__ Bt,
                    const float* __restrict__ bias, float* __restrict__ C,
                    int M, int N, int K) {
  __shared__ ushort_t As[128 * 32];
  __shared__ ushort_t Bs[128 * 32];
  const int tid = threadIdx.x;
  const int w = tid >> 6, l = tid & 63;
  const int m0 = blockIdx.x * 128, n0 = blockIdx.y * 128;
  const int wr = w >> 1, wc = w & 1;
  const int fr = l & 15, fk = (l >> 4) * 8;

  f32x4 acc[4][4] = {};

  for (int k0 = 0; k0 < K; k0 += 32) {
    __syncthreads();
#pragma unroll
    for (int p = 0; p < 2; ++p) {
      int c = p * 256 + tid;
      int row = c >> 2, col = (c & 3) * 8;
      GLOAD_LDS16(&A[(size_t)(m0 + row) * K + k0 + col], &As[c * 8]);
      GLOAD_LDS16(&Bt[(size_t)(n0 + row) * K + k0 + col], &Bs[c * 8]);
    }
    __syncthreads();
    short8 af[4], bf[4];
#pragma unroll
    for (int mi = 0; mi < 4; ++mi) af[mi] = *(const short8*)(&As[(wr * 64 + mi * 16 + fr) * 32 + fk]);
#pragma unroll
    for (int ni = 0; ni < 4; ++ni) bf[ni] = *(const short8*)(&Bs[(wc * 64 + ni * 16 + fr) * 32 + fk]);
#pragma unroll
    for (int mi = 0; mi < 4; ++mi)
#pragma unroll
      for (int ni = 0; ni < 4; ++ni)
        acc[mi][ni] = MFMA_BF16(af[mi], bf[ni], acc[mi][ni]);
  }

#pragma unroll
  for (int ni = 0; ni < 4; ++ni) {
    int col = n0 + wc * 64 + ni * 16 + fr;
    float bv = bias[col];
#pragma unroll
    for (int mi = 0; mi < 4; ++mi) {
#pragma unroll
      for (int q = 0; q < 4; ++q) {
        int row = m0 + wr * 64 + mi * 16 + (l >> 4) * 4 + q;
        C[(size_t)row * N + col] = acc[mi][ni][q] + bv;
      }
    }
  }
}

// ---------------- merged QKV + pos GEMM: (256,4) occupancy bump ----------------
__global__ __launch_bounds__(256, 4)
void gemm_qkvpos_kernel(const ushort_t* __restrict__ x_bf, const ushort_t* __restrict__ in_w_bf,
                        const float* __restrict__ in_b,
                        const float* __restrict__ rwb, const float* __restrict__ rrb,
                        const ushort_t* __restrict__ posx_bf, const ushort_t* __restrict__ pos_w_bf,
                        const float* __restrict__ pos_b,
                        ushort_t* __restrict__ qrw, ushort_t* __restrict__ qrr,
                        ushort_t* __restrict__ kbuf, ushort_t* __restrict__ vt,
                        ushort_t* __restrict__ rhp) {
  __shared__ ushort_t As[128 * 32];
  __shared__ ushort_t Bs[128 * 32];
  const int K = 1024;
  const int tid = threadIdx.x;
  const int w = tid >> 6, l = tid & 63;
  const int bid = blockIdx.x;
  const bool isPos = bid >= 768;
  int m0, n0;
  const ushort_t *A, *Bt;
  if (!isPos) {
    m0 = (bid & 31) * 128; n0 = (bid >> 5) * 128; A = x_bf; Bt = in_w_bf;
  } else {
    int pb2 = bid - 768;
    m0 = (pb2 & 7) * 128; n0 = (pb2 >> 3) * 128; A = posx_bf; Bt = pos_w_bf;
  }
  const int wr = w >> 1, wc = w & 1;
  const int fr = l & 15, fk = (l >> 4) * 8;

  f32x4 acc[4][4] = {};

  for (int k0 = 0; k0 < K; k0 += 32) {
    __syncthreads();
#pragma unroll
    for (int p = 0; p < 2; ++p) {
      int c = p * 256 + tid;
      int row = c >> 2, col = (c & 3) * 8;
      GLOAD_LDS16(&A[(size_t)(m0 + row) * K + k0 + col], &As[c * 8]);
      GLOAD_LDS16(&Bt[(size_t)(n0 + row) * K + k0 + col], &Bs[c * 8]);
    }
    __syncthreads();
    short8 af[4], bf[4];
#pragma unroll
    for (int mi = 0; mi < 4; ++mi) af[mi] = *(const short8*)(&As[(wr * 64 + mi * 16 + fr) * 32 + fk]);
#pragma unroll
    for (int ni = 0; ni < 4; ++ni) bf[ni] = *(const short8*)(&Bs[(wc * 64 + ni * 16 + fr) * 32 + fk]);
#pragma unroll
    for (int mi = 0; mi < 4; ++mi)
#pragma unroll
      for (int ni = 0; ni < 4; ++ni)
        acc[mi][ni] = MFMA_BF16(af[mi], bf[ni], acc[mi][ni]);
  }

  if (!isPos) {
#pragma unroll
    for (int ni = 0; ni < 4; ++ni) {
      int col = n0 + wc * 64 + ni * 16 + fr;
      int part = col >> 10;
      int e = col & 1023;
      int hh = e >> 6, dd = e & 63;
      float bv = in_b[col];
      float rwv = rwb[e];
      float rrv = rrb[e];
#pragma unroll
      for (int mi = 0; mi < 4; ++mi) {
#pragma unroll
        for (int q = 0; q < 4; ++q) {
          int row = m0 + wr * 64 + mi * 16 + (l >> 4) * 4 + q;
          int t = row >> 2, b = row & 3;
          float v = acc[mi][ni][q] + bv;
          if (part == 0) {
            unsigned idx = (((unsigned)(b * 16 + hh) * 1024 + t) << 6) + dd;
            qrw[idx] = f2bf(v + rwv);
            qrr[idx] = f2bf(v + rrv);
          } else if (part == 1) {
            unsigned idx = (((unsigned)(b * 16 + hh) * 1024 + t) << 6) + dd;
            kbuf[idx] = f2bf(v);
          } else {
            vt[(((unsigned)(b * 16 + hh) * 64 + dd) << 10) + t] = f2bf(v);
          }
        }
      }
    }
  } else {
#pragma unroll
    for (int ni = 0; ni < 4; ++ni) {
      int col = n0 + wc * 64 + ni * 16 + fr;
      int hh = col >> 6, dd = col & 63;
      float bv = pos_b[col];
#pragma unroll
      for (int mi = 0; mi < 4; ++mi) {
#pragma unroll
        for (int q = 0; q < 4; ++q) {
          int t = m0 + wr * 64 + mi * 16 + (l >> 4) * 4 + q;
          rhp[((unsigned)hh * 1152 + 64 + t) * 64 + dd] = f2bf(acc[mi][ni][q] + bv);
        }
      }
    }
  }
}

// ---------------- attn v9 (unchanged from R19) ----------------
__global__ __launch_bounds__(256, 2)
void attn_kernel(const ushort_t* __restrict__ qrw, const ushort_t* __restrict__ qrr,
                 const ushort_t* __restrict__ kb, const ushort_t* __restrict__ vt,
                 const ushort_t* __restrict__ rhp, ushort_t* __restrict__ ctx) {
  __shared__ __attribute__((aligned(16))) ushort_t KV[2][4096];  // per buf: K[32][64] | V[64][32], 8KB
  __shared__ __attribute__((aligned(16))) char PtB[4][1024];     // per wave: P[16][32] bf16, chunk-swizzled

  const int tid = threadIdx.x, w = tid >> 6, l = tid & 63;
  const int bid = blockIdx.x;
  const int g = bid & 63;
  const int h = ((g & 7) << 1) | ((g >> 3) & 1);   // bid%8 -> head-pair (XCD L2 locality)
  const int b = g >> 4;
  const int bh = b * 16 + h;
  const int sx = 15 - (bid >> 6);                  // reversed: big strips first
  const int istrip = sx * 64 + w * 16;
  const int fr = l & 15, fkq = (l >> 4) * 8;
  const float scale = 0.125f;
  char* Pw = PtB[w];
  const int njt = (sx + 1) * 2;                    // 32-col tiles, block-uniform
  const int jlim = istrip + 15;                    // wave compute bound
  const unsigned swzr = (unsigned)(fr & 7) << 4;
  const unsigned swzp = (unsigned)((fr >> 1) & 3) << 4;

  short8 aqw0, aqw1, aqr0, aqr1;
  {
    unsigned qb = ((unsigned)bh * T_LEN + istrip + fr) * 64 + fkq;
    aqw0 = *(const short8*)(qrw + qb);
    aqw1 = *(const short8*)(qrw + qb + 32);
    aqr0 = *(const short8*)(qrr + qb);
    aqr1 = *(const short8*)(qrr + qb + 32);
  }

  const int krow = tid >> 3;
  const int kci8 = ((tid & 7) ^ (krow & 7)) * 8;
  const int vdr = tid >> 2;
  const int vci8 = ((tid & 3) ^ ((vdr >> 1) & 3)) * 8;
  const ushort_t* kgbase = kb + ((unsigned)bh * 1024 + krow) * 64 + kci8;
  const ushort_t* vgbase = vt + ((unsigned)bh * 64 + vdr) * 1024 + vci8;

  const unsigned rbase = ((unsigned)h * 1152 + 64 + 1008 - istrip + fr) * 64 + fkq;

  float s_run[4] = {0.f, 0.f, 0.f, 0.f};
  f32x4 o[4] = {};

#define STAGE(J0, BUF)                                                    \
  do {                                                                    \
    ushort_t* Kd = (ushort_t*)KV[BUF];                                    \
    GLOAD_LDS16(kgbase + (unsigned)(J0) * 64, Kd + tid * 8);              \
    GLOAD_LDS16(vgbase + (unsigned)(J0), Kd + 2048 + tid * 8);            \
  } while (0)

  STAGE(0, 0);
  __syncthreads();

  for (int jt = 0; jt < njt; ++jt) {
    const int j0 = jt << 5;
    const int buf = jt & 1;
    if (jt + 1 < njt) STAGE((jt + 1) << 5, buf ^ 1);

    if (j0 <= jlim) {
      const char* KS = (const char*)KV[buf];

      short8 rf[6];
      {
        unsigned roff = rbase + (unsigned)j0 * 64;
#pragma unroll
        for (int f = 0; f < 3; ++f) {
          rf[2 * f] = *(const short8*)(rhp + roff + f * 1024);
          rf[2 * f + 1] = *(const short8*)(rhp + roff + f * 1024 + 32);
        }
      }
      f32x4 ac0 = {0, 0, 0, 0}, ac1 = {0, 0, 0, 0};
      f32x4 pb0 = {0, 0, 0, 0}, pb1 = {0, 0, 0, 0}, pb2 = {0, 0, 0, 0};
      {
        short8 kf00 = *(const short8*)(KS + (unsigned)fr * 128 + (((unsigned)fkq * 2) ^ swzr));
        short8 kf01 = *(const short8*)(KS + (unsigned)fr * 128 + (((unsigned)(64 + fkq * 2)) ^ swzr));
        short8 kf10 = *(const short8*)(KS + (unsigned)(16 + fr) * 128 + (((unsigned)fkq * 2) ^ swzr));
        short8 kf11 = *(const short8*)(KS + (unsigned)(16 + fr) * 128 + (((unsigned)(64 + fkq * 2)) ^ swzr));
        ac0 = MFMA_BF16(aqw0, kf00, ac0);
        ac0 = MFMA_BF16(aqw1, kf01, ac0);
        ac1 = MFMA_BF16(aqw0, kf10, ac1);
        ac1 = MFMA_BF16(aqw1, kf11, ac1);
      }
      pb0 = MFMA_BF16(aqr0, rf[0], pb0);
      pb0 = MFMA_BF16(aqr1, rf[1], pb0);
      pb1 = MFMA_BF16(aqr0, rf[2], pb1);
      pb1 = MFMA_BF16(aqr1, rf[3], pb1);
      pb2 = MFMA_BF16(aqr0, rf[4], pb2);
      pb2 = MFMA_BF16(aqr1, rf[5], pb2);

#pragma unroll
      for (int q = 0; q < 4; ++q) {
        int ri = 4 * (l >> 4) + q;
        int e = 15 + fr - ri;
        int src = (l & 48) | (e & 15);
        float sh0 = __shfl(pb0[q], src, 64);
        float sh1 = __shfl(pb1[q], src, 64);
        float sh2 = __shfl(pb2[q], src, 64);
        int hi = e >> 4;
        float pv0 = hi ? sh1 : sh0;
        float pv1 = hi ? sh2 : sh1;
        int ig = istrip + ri;
        float s0 = (ac0[q] + pv0) * scale - 20.0f;
        float s1 = (ac1[q] + pv1) * scale - 20.0f;
        float p0 = (j0 + fr > ig) ? 0.f : __expf(s0);
        float p1 = (j0 + 16 + fr > ig) ? 0.f : __expf(s1);
        unsigned psw = (unsigned)((ri >> 1) & 3) << 4;
        *(ushort_t*)(Pw + ri * 64 + (((unsigned)(fr * 2)) ^ psw)) = f2bf(p0);
        *(ushort_t*)(Pw + ri * 64 + (((unsigned)(32 + fr * 2)) ^ psw)) = f2bf(p1);
        s_run[q] += p0 + p1;
      }

      {
        short8 pa = *(const short8*)(Pw + (unsigned)fr * 64 + (((unsigned)fkq * 2) ^ swzp));
#pragma unroll
        for (int dg = 0; dg < 4; ++dg) {
          int vrow = dg * 16 + fr;
          short8 vf = *(const short8*)(KS + 4096 + (unsigned)vrow * 64 +
                                       (((unsigned)fkq * 2) ^ ((unsigned)((vrow >> 1) & 3) << 4)));
          o[dg] = MFMA_BF16(pa, vf, o[dg]);
        }
      }
    }

    __syncthreads();
  }

#pragma unroll
  for (int q = 0; q < 4; ++q) {
    float sq = s_run[q];
#pragma unroll
    for (int o2 = 8; o2; o2 >>= 1) sq += __shfl_xor(sq, o2, 64);
    s_run[q] = sq;
  }
#pragma unroll
  for (int dg = 0; dg < 4; ++dg) {
#pragma unroll
    for (int q = 0; q < 4; ++q) {
      int ig = istrip + 4 * (l >> 4) + q;
      int dd = dg * 16 + fr;
      ctx[((size_t)ig * BATCH + b) * EMB + h * 64 + dd] = f2bf(o[dg][q] / s_run[q]);
    }
  }
}

// ---------------- launch ----------------
extern "C" void kernel_launch(void* const* d_in, const int* in_sizes, int n_in,
                              void* d_out, int out_size, void* d_ws, size_t ws_size,
                              hipStream_t stream) {
  (void)in_sizes; (void)n_in; (void)out_size; (void)ws_size;
  const float* x = (const float*)d_in[0];
  const float* pos = (const float*)d_in[1];
  const float* in_w_mu = (const float*)d_in[3];
  const float* in_w_rho = (const float*)d_in[4];
  const float* in_w_eps = (const float*)d_in[5];
  const float* in_b_mu = (const float*)d_in[6];
  const float* in_b_rho = (const float*)d_in[7];
  const float* in_b_eps = (const float*)d_in[8];
  const float* pos_w_mu = (const float*)d_in[9];
  const float* pos_w_rho = (const float*)d_in[10];
  const float* pos_w_eps = (const float*)d_in[11];
  const float* pos_b_mu = (const float*)d_in[12];
  const float* pos_b_rho = (const float*)d_in[13];
  const float* pos_b_eps = (const float*)d_in[14];
  const float* out_w_mu = (const float*)d_in[15];
  const float* out_w_rho = (const float*)d_in[16];
  const float* out_w_eps = (const float*)d_in[17];
  const float* out_b_mu = (const float*)d_in[18];
  const float* out_b_rho = (const float*)d_in[19];
  const float* out_b_eps = (const float*)d_in[20];
  const float* rw_mu = (const float*)d_in[21];
  const float* rw_rho = (const float*)d_in[22];
  const float* rw_eps = (const float*)d_in[23];
  const float* rr_mu = (const float*)d_in[24];
  const float* rr_rho = (const float*)d_in[25];
  const float* rr_eps = (const float*)d_in[26];

  char* ws = (char*)d_ws;
  ushort_t* in_w_bf  = (ushort_t*)(ws + 0);
  ushort_t* pos_w_bf = (ushort_t*)(ws + 6291456);
  ushort_t* out_w_bf = (ushort_t*)(ws + 8388608);
  float* in_b  = (float*)(ws + 10485760);
  float* pos_b = (float*)(ws + 10498048);
  float* out_b = (float*)(ws + 10502144);
  float* rwb   = (float*)(ws + 10506240);
  float* rrb   = (float*)(ws + 10510336);
  ushort_t* x_bf    = (ushort_t*)(ws + 10514432);
  ushort_t* posx_bf = (ushort_t*)(ws + 18903040);
  ushort_t* qrw = (ushort_t*)(ws + 21000192);
  ushort_t* qrr = (ushort_t*)(ws + 29388800);
  ushort_t* kb  = (ushort_t*)(ws + 37777408);
  ushort_t* vt  = (ushort_t*)(ws + 46166016);
  ushort_t* rhp = (ushort_t*)(ws + 54554624);
  ushort_t* ctx = (ushort_t*)(ws + 56913920);

  sample_w_kernel<<<5120, 256, 0, stream>>>(in_w_mu, in_w_rho, in_w_eps, in_w_bf,
                                            pos_w_mu, pos_w_rho, pos_w_eps, pos_w_bf,
                                            out_w_mu, out_w_rho, out_w_eps, out_w_bf);
  sample_bias_kernel<<<28, 256, 0, stream>>>(in_b_mu, in_b_rho, in_b_eps, in_b,
                                             pos_b_mu, pos_b_rho, pos_b_eps, pos_b,
                                             out_b_mu, out_b_rho, out_b_eps, out_b,
                                             rw_mu, rw_rho, rw_eps, rwb,
                                             rr_mu, rr_rho, rr_eps, rrb);
  cast_bf16x4_kernel<<<4096, 256, 0, stream>>>(x, x_bf, 1048576);
  cast_bf16x4_kernel<<<1024, 256, 0, stream>>>(pos, posx_bf, 262144);
  zero_rhp_pad_kernel<<<512, 256, 0, stream>>>(rhp);

  gemm_qkvpos_kernel<<<832, 256, 0, stream>>>(x_bf, in_w_bf, in_b, rwb, rrb,
                                              posx_bf, pos_w_bf, pos_b,
                                              qrw, qrr, kb, vt, rhp);

  attn_kernel<<<dim3(1024), 256, 0, stream>>>(qrw, qrr, kb, vt, rhp, ctx);

  gemm_bt_kernel<<<dim3(32, 8), 256, 0, stream>>>(ctx, out_w_bf, out_b, (float*)d_out, 4096, 1024, 1024);
}

// Round 21
// 166.217 us; speedup vs baseline: 2.4368x; 1.0216x over previous
//
#include <hip/hip_runtime.h>

typedef unsigned short ushort_t;
typedef __attribute__((ext_vector_type(8))) short short8;
typedef __attribute__((ext_vector_type(4))) float f32x4;
typedef __attribute__((ext_vector_type(4))) unsigned short ush4;

#define MFMA_BF16(a, b, c) __builtin_amdgcn_mfma_f32_16x16x32_bf16((a), (b), (c), 0, 0, 0)

#define GLOAD_LDS16(GP, LP)                                                       \
  __builtin_amdgcn_global_load_lds(                                               \
      (const __attribute__((address_space(1))) void*)(GP),                        \
      (__attribute__((address_space(3))) void*)(LP), 16, 0, 0)

#define T_LEN 1024
#define BATCH 4
#define NHEAD 16
#define DHEAD 64
#define EMB 1024

__device__ __forceinline__ ushort_t f2bf(float f) {
  unsigned u = __float_as_uint(f);
  u += 0x7fffu + ((u >> 16) & 1u);
  return (ushort_t)(u >> 16);
}

// ---------------- elementwise ----------------
__global__ void sample_w_kernel(const float* __restrict__ im, const float* __restrict__ ir,
                                const float* __restrict__ ie, ushort_t* __restrict__ io,
                                const float* __restrict__ pm, const float* __restrict__ pr,
                                const float* __restrict__ pe, ushort_t* __restrict__ po,
                                const float* __restrict__ om, const float* __restrict__ orh,
                                const float* __restrict__ oe, ushort_t* __restrict__ oo) {
  int i = blockIdx.x * 256 + threadIdx.x;
  const float *mu, *rho, *eps;
  ushort_t* out;
  int j;
  if (i < 786432) { mu = im; rho = ir; eps = ie; out = io; j = i; }
  else if (i < 1048576) { mu = pm; rho = pr; eps = pe; out = po; j = i - 786432; }
  else { mu = om; rho = orh; eps = oe; out = oo; j = i - 1048576; }
  f32x4 m = *(const f32x4*)(mu + (size_t)j * 4);
  f32x4 r = *(const f32x4*)(rho + (size_t)j * 4);
  f32x4 e = *(const f32x4*)(eps + (size_t)j * 4);
  ush4 o;
#pragma unroll
  for (int k = 0; k < 4; ++k) o[k] = f2bf(m[k] + log1pf(__expf(r[k])) * e[k]);
  *(ush4*)(out + (size_t)j * 4) = o;
}

__global__ void sample_bias_kernel(
    const float* __restrict__ am, const float* __restrict__ ar, const float* __restrict__ ae, float* __restrict__ ao,
    const float* __restrict__ bm, const float* __restrict__ br, const float* __restrict__ be, float* __restrict__ bo,
    const float* __restrict__ cm, const float* __restrict__ cr, const float* __restrict__ ce, float* __restrict__ co,
    const float* __restrict__ dm, const float* __restrict__ dr, const float* __restrict__ de, float* __restrict__ dof,
    const float* __restrict__ em, const float* __restrict__ er, const float* __restrict__ ee, float* __restrict__ eo) {
  int i = blockIdx.x * 256 + threadIdx.x;
  if (i < 3072) {
    ao[i] = am[i] + log1pf(__expf(ar[i])) * ae[i];
  } else if (i < 4096) {
    int j = i - 3072; bo[j] = bm[j] + log1pf(__expf(br[j])) * be[j];
  } else if (i < 5120) {
    int j = i - 4096; co[j] = cm[j] + log1pf(__expf(cr[j])) * ce[j];
  } else if (i < 6144) {
    int j = i - 5120; dof[j] = dm[j] + log1pf(__expf(dr[j])) * de[j];
  } else if (i < 7168) {
    int j = i - 6144; eo[j] = em[j] + log1pf(__expf(er[j])) * ee[j];
  }
}

__global__ void cast_bf16x4_kernel(const float* __restrict__ in, ushort_t* __restrict__ out, int n4) {
  int i = blockIdx.x * 256 + threadIdx.x;
  if (i < n4) {
    f32x4 v = *(const f32x4*)(in + (size_t)i * 4);
    ush4 o;
#pragma unroll
    for (int j = 0; j < 4; ++j) o[j] = f2bf(v[j]);
    *(ush4*)(out + (size_t)i * 4) = o;
  }
}

__global__ void zero_rhp_pad_kernel(ushort_t* __restrict__ rhp) {
  int idx = blockIdx.x * 256 + threadIdx.x;
  int dd = idx & 63;
  int pr = (idx >> 6) & 127;
  int h = idx >> 13;
  int phys = (pr < 64) ? pr : (pr - 64 + 1088);
  rhp[((size_t)h * 1152 + phys) * 64 + dd] = 0;
}

// ---------------- GEMM BK=64 staging helpers ----------------
// LDS tile [128 rows][64 cols] bf16, linear dest; SOURCE col chunk pre-swizzled
// (c&7)^(row&7) so read-side XOR lands 2-way bank aliasing (free).
#define GSTAGE64(SRC, LDSDST, LD)                                                 \
  do {                                                                            \
    _Pragma("unroll")                                                             \
    for (int p_ = 0; p_ < 4; ++p_) {                                              \
      int c_ = p_ * 256 + tid;                                                    \
      int row_ = c_ >> 3;                                                         \
      int scol_ = ((c_ & 7) ^ (row_ & 7)) * 8;                                    \
      GLOAD_LDS16((SRC) + (size_t)row_ * (LD) + scol_, (LDSDST) + c_ * 8);        \
    }                                                                             \
  } while (0)

// fragment read: row, global col chunk j -> LDS byte row*128 + ((j ^ (row&7))<<4)
#define FRAG64(LDS, ROW, JCH) \
  (*(const short8*)((const char*)(LDS) + (unsigned)(ROW) * 128 + ((unsigned)((JCH) ^ ((ROW) & 7)) << 4)))

// ---------------- GEMM (out-proj), BK=64 ----------------
__global__ __launch_bounds__(256, 4)
void gemm_bt_kernel(const ushort_t* __restrict__ A, const ushort_t* __restrict__ Bt,
                    const float* __restrict__ bias, float* __restrict__ C,
                    int M, int N, int K) {
  __shared__ ushort_t As[128 * 64];
  __shared__ ushort_t Bs[128 * 64];
  const int tid = threadIdx.x;
  const int w = tid >> 6, l = tid & 63;
  const int m0 = blockIdx.x * 128, n0 = blockIdx.y * 128;
  const int wr = w >> 1, wc = w & 1;
  const int fr = l & 15, fj = l >> 4;              // fj = k-chunk index base (0..3)

  f32x4 acc[4][4] = {};

  for (int k0 = 0; k0 < K; k0 += 64) {
    __syncthreads();
    GSTAGE64(A + (size_t)m0 * K + k0, As, K);
    GSTAGE64(Bt + (size_t)n0 * K + k0, Bs, K);
    __syncthreads();
#pragma unroll
    for (int kh = 0; kh < 2; ++kh) {
      short8 af[4], bf[4];
#pragma unroll
      for (int mi = 0; mi < 4; ++mi) af[mi] = FRAG64(As, wr * 64 + mi * 16 + fr, kh * 4 + fj);
#pragma unroll
      for (int ni = 0; ni < 4; ++ni) bf[ni] = FRAG64(Bs, wc * 64 + ni * 16 + fr, kh * 4 + fj);
#pragma unroll
      for (int mi = 0; mi < 4; ++mi)
#pragma unroll
        for (int ni = 0; ni < 4; ++ni)
          acc[mi][ni] = MFMA_BF16(af[mi], bf[ni], acc[mi][ni]);
    }
  }

#pragma unroll
  for (int ni = 0; ni < 4; ++ni) {
    int col = n0 + wc * 64 + ni * 16 + fr;
    float bv = bias[col];
#pragma unroll
    for (int mi = 0; mi < 4; ++mi) {
#pragma unroll
      for (int q = 0; q < 4; ++q) {
        int row = m0 + wr * 64 + mi * 16 + (l >> 4) * 4 + q;
        C[(size_t)row * N + col] = acc[mi][ni][q] + bv;
      }
    }
  }
}

// ---------------- merged QKV + pos GEMM, BK=64 ----------------
__global__ __launch_bounds__(256, 4)
void gemm_qkvpos_kernel(const ushort_t* __restrict__ x_bf, const ushort_t* __restrict__ in_w_bf,
                        const float* __restrict__ in_b,
                        const float* __restrict__ rwb, const float* __restrict__ rrb,
                        const ushort_t* __restrict__ posx_bf, const ushort_t* __restrict__ pos_w_bf,
                        const float* __restrict__ pos_b,
                        ushort_t* __restrict__ qrw, ushort_t* __restrict__ qrr,
                        ushort_t* __restrict__ kbuf, ushort_t* __restrict__ vt,
                        ushort_t* __restrict__ rhp) {
  __shared__ ushort_t As[128 * 64];
  __shared__ ushort_t Bs[128 * 64];
  const int K = 1024;
  const int tid = threadIdx.x;
  const int w = tid >> 6, l = tid & 63;
  const int bid = blockIdx.x;
  const bool isPos = bid >= 768;
  int m0, n0;
  const ushort_t *A, *Bt;
  if (!isPos) {
    m0 = (bid & 31) * 128; n0 = (bid >> 5) * 128; A = x_bf; Bt = in_w_bf;
  } else {
    int pb2 = bid - 768;
    m0 = (pb2 & 7) * 128; n0 = (pb2 >> 3) * 128; A = posx_bf; Bt = pos_w_bf;
  }
  const int wr = w >> 1, wc = w & 1;
  const int fr = l & 15, fj = l >> 4;

  f32x4 acc[4][4] = {};

  for (int k0 = 0; k0 < K; k0 += 64) {
    __syncthreads();
    GSTAGE64(A + (size_t)m0 * K + k0, As, K);
    GSTAGE64(Bt + (size_t)n0 * K + k0, Bs, K);
    __syncthreads();
#pragma unroll
    for (int kh = 0; kh < 2; ++kh) {
      short8 af[4], bf[4];
#pragma unroll
      for (int mi = 0; mi < 4; ++mi) af[mi] = FRAG64(As, wr * 64 + mi * 16 + fr, kh * 4 + fj);
#pragma unroll
      for (int ni = 0; ni < 4; ++ni) bf[ni] = FRAG64(Bs, wc * 64 + ni * 16 + fr, kh * 4 + fj);
#pragma unroll
      for (int mi = 0; mi < 4; ++mi)
#pragma unroll
        for (int ni = 0; ni < 4; ++ni)
          acc[mi][ni] = MFMA_BF16(af[mi], bf[ni], acc[mi][ni]);
    }
  }

  if (!isPos) {
#pragma unroll
    for (int ni = 0; ni < 4; ++ni) {
      int col = n0 + wc * 64 + ni * 16 + fr;
      int part = col >> 10;
      int e = col & 1023;
      int hh = e >> 6, dd = e & 63;
      float bv = in_b[col];
      float rwv = rwb[e];
      float rrv = rrb[e];
#pragma unroll
      for (int mi = 0; mi < 4; ++mi) {
#pragma unroll
        for (int q = 0; q < 4; ++q) {
          int row = m0 + wr * 64 + mi * 16 + (l >> 4) * 4 + q;
          int t = row >> 2, b = row & 3;
          float v = acc[mi][ni][q] + bv;
          if (part == 0) {
            unsigned idx = (((unsigned)(b * 16 + hh) * 1024 + t) << 6) + dd;
            qrw[idx] = f2bf(v + rwv);
            qrr[idx] = f2bf(v + rrv);
          } else if (part == 1) {
            unsigned idx = (((unsigned)(b * 16 + hh) * 1024 + t) << 6) + dd;
            kbuf[idx] = f2bf(v);
          } else {
            vt[(((unsigned)(b * 16 + hh) * 64 + dd) << 10) + t] = f2bf(v);
          }
        }
      }
    }
  } else {
#pragma unroll
    for (int ni = 0; ni < 4; ++ni) {
      int col = n0 + wc * 64 + ni * 16 + fr;
      int hh = col >> 6, dd = col & 63;
      float bv = pos_b[col];
#pragma unroll
      for (int mi = 0; mi < 4; ++mi) {
#pragma unroll
        for (int q = 0; q < 4; ++q) {
          int t = m0 + wr * 64 + mi * 16 + (l >> 4) * 4 + q;
          rhp[((unsigned)hh * 1152 + 64 + t) * 64 + dd] = f2bf(acc[mi][ni][q] + bv);
        }
      }
    }
  }
}

// ---------------- attn v9 (unchanged from R19) ----------------
__global__ __launch_bounds__(256, 2)
void attn_kernel(const ushort_t* __restrict__ qrw, const ushort_t* __restrict__ qrr,
                 const ushort_t* __restrict__ kb, const ushort_t* __restrict__ vt,
                 const ushort_t* __restrict__ rhp, ushort_t* __restrict__ ctx) {
  __shared__ __attribute__((aligned(16))) ushort_t KV[2][4096];
  __shared__ __attribute__((aligned(16))) char PtB[4][1024];

  const int tid = threadIdx.x, w = tid >> 6, l = tid & 63;
  const int bid = blockIdx.x;
  const int g = bid & 63;
  const int h = ((g & 7) << 1) | ((g >> 3) & 1);
  const int b = g >> 4;
  const int bh = b * 16 + h;
  const int sx = 15 - (bid >> 6);
  const int istrip = sx * 64 + w * 16;
  const int fr = l & 15, fkq = (l >> 4) * 8;
  const float scale = 0.125f;
  char* Pw = PtB[w];
  const int njt = (sx + 1) * 2;
  const int jlim = istrip + 15;
  const unsigned swzr = (unsigned)(fr & 7) << 4;
  const unsigned swzp = (unsigned)((fr >> 1) & 3) << 4;

  short8 aqw0, aqw1, aqr0, aqr1;
  {
    unsigned qb = ((unsigned)bh * T_LEN + istrip + fr) * 64 + fkq;
    aqw0 = *(const short8*)(qrw + qb);
    aqw1 = *(const short8*)(qrw + qb + 32);
    aqr0 = *(const short8*)(qrr + qb);
    aqr1 = *(const short8*)(qrr + qb + 32);
  }

  const int krow = tid >> 3;
  const int kci8 = ((tid & 7) ^ (krow & 7)) * 8;
  const int vdr = tid >> 2;
  const int vci8 = ((tid & 3) ^ ((vdr >> 1) & 3)) * 8;
  const ushort_t* kgbase = kb + ((unsigned)bh * 1024 + krow) * 64 + kci8;
  const ushort_t* vgbase = vt + ((unsigned)bh * 64 + vdr) * 1024 + vci8;

  const unsigned rbase = ((unsigned)h * 1152 + 64 + 1008 - istrip + fr) * 64 + fkq;

  float s_run[4] = {0.f, 0.f, 0.f, 0.f};
  f32x4 o[4] = {};

#define STAGE(J0, BUF)                                                    \
  do {                                                                    \
    ushort_t* Kd = (ushort_t*)KV[BUF];                                    \
    GLOAD_LDS16(kgbase + (unsigned)(J0) * 64, Kd + tid * 8);              \
    GLOAD_LDS16(vgbase + (unsigned)(J0), Kd + 2048 + tid * 8);            \
  } while (0)

  STAGE(0, 0);
  __syncthreads();

  for (int jt = 0; jt < njt; ++jt) {
    const int j0 = jt << 5;
    const int buf = jt & 1;
    if (jt + 1 < njt) STAGE((jt + 1) << 5, buf ^ 1);

    if (j0 <= jlim) {
      const char* KS = (const char*)KV[buf];

      short8 rf[6];
      {
        unsigned roff = rbase + (unsigned)j0 * 64;
#pragma unroll
        for (int f = 0; f < 3; ++f) {
          rf[2 * f] = *(const short8*)(rhp + roff + f * 1024);
          rf[2 * f + 1] = *(const short8*)(rhp + roff + f * 1024 + 32);
        }
      }
      f32x4 ac0 = {0, 0, 0, 0}, ac1 = {0, 0, 0, 0};
      f32x4 pb0 = {0, 0, 0, 0}, pb1 = {0, 0, 0, 0}, pb2 = {0, 0, 0, 0};
      {
        short8 kf00 = *(const short8*)(KS + (unsigned)fr * 128 + (((unsigned)fkq * 2) ^ swzr));
        short8 kf01 = *(const short8*)(KS + (unsigned)fr * 128 + (((unsigned)(64 + fkq * 2)) ^ swzr));
        short8 kf10 = *(const short8*)(KS + (unsigned)(16 + fr) * 128 + (((unsigned)fkq * 2) ^ swzr));
        short8 kf11 = *(const short8*)(KS + (unsigned)(16 + fr) * 128 + (((unsigned)(64 + fkq * 2)) ^ swzr));
        ac0 = MFMA_BF16(aqw0, kf00, ac0);
        ac0 = MFMA_BF16(aqw1, kf01, ac0);
        ac1 = MFMA_BF16(aqw0, kf10, ac1);
        ac1 = MFMA_BF16(aqw1, kf11, ac1);
      }
      pb0 = MFMA_BF16(aqr0, rf[0], pb0);
      pb0 = MFMA_BF16(aqr1, rf[1], pb0);
      pb1 = MFMA_BF16(aqr0, rf[2], pb1);
      pb1 = MFMA_BF16(aqr1, rf[3], pb1);
      pb2 = MFMA_BF16(aqr0, rf[4], pb2);
      pb2 = MFMA_BF16(aqr1, rf[5], pb2);

#pragma unroll
      for (int q = 0; q < 4; ++q) {
        int ri = 4 * (l >> 4) + q;
        int e = 15 + fr - ri;
        int src = (l & 48) | (e & 15);
        float sh0 = __shfl(pb0[q], src, 64);
        float sh1 = __shfl(pb1[q], src, 64);
        float sh2 = __shfl(pb2[q], src, 64);
        int hi = e >> 4;
        float pv0 = hi ? sh1 : sh0;
        float pv1 = hi ? sh2 : sh1;
        int ig = istrip + ri;
        float s0 = (ac0[q] + pv0) * scale - 20.0f;
        float s1 = (ac1[q] + pv1) * scale - 20.0f;
        float p0 = (j0 + fr > ig) ? 0.f : __expf(s0);
        float p1 = (j0 + 16 + fr > ig) ? 0.f : __expf(s1);
        unsigned psw = (unsigned)((ri >> 1) & 3) << 4;
        *(ushort_t*)(Pw + ri * 64 + (((unsigned)(fr * 2)) ^ psw)) = f2bf(p0);
        *(ushort_t*)(Pw + ri * 64 + (((unsigned)(32 + fr * 2)) ^ psw)) = f2bf(p1);
        s_run[q] += p0 + p1;
      }

      {
        short8 pa = *(const short8*)(Pw + (unsigned)fr * 64 + (((unsigned)fkq * 2) ^ swzp));
#pragma unroll
        for (int dg = 0; dg < 4; ++dg) {
          int vrow = dg * 16 + fr;
          short8 vf = *(const short8*)(KS + 4096 + (unsigned)vrow * 64 +
                                       (((unsigned)fkq * 2) ^ ((unsigned)((vrow >> 1) & 3) << 4)));
          o[dg] = MFMA_BF16(pa, vf, o[dg]);
        }
      }
    }

    __syncthreads();
  }

#pragma unroll
  for (int q = 0; q < 4; ++q) {
    float sq = s_run[q];
#pragma unroll
    for (int o2 = 8; o2; o2 >>= 1) sq += __shfl_xor(sq, o2, 64);
    s_run[q] = sq;
  }
#pragma unroll
  for (int dg = 0; dg < 4; ++dg) {
#pragma unroll
    for (int q = 0; q < 4; ++q) {
      int ig = istrip + 4 * (l >> 4) + q;
      int dd = dg * 16 + fr;
      ctx[((size_t)ig * BATCH + b) * EMB + h * 64 + dd] = f2bf(o[dg][q] / s_run[q]);
    }
  }
}

// ---------------- launch ----------------
extern "C" void kernel_launch(void* const* d_in, const int* in_sizes, int n_in,
                              void* d_out, int out_size, void* d_ws, size_t ws_size,
                              hipStream_t stream) {
  (void)in_sizes; (void)n_in; (void)out_size; (void)ws_size;
  const float* x = (const float*)d_in[0];
  const float* pos = (const float*)d_in[1];
  const float* in_w_mu = (const float*)d_in[3];
  const float* in_w_rho = (const float*)d_in[4];
  const float* in_w_eps = (const float*)d_in[5];
  const float* in_b_mu = (const float*)d_in[6];
  const float* in_b_rho = (const float*)d_in[7];
  const float* in_b_eps = (const float*)d_in[8];
  const float* pos_w_mu = (const float*)d_in[9];
  const float* pos_w_rho = (const float*)d_in[10];
  const float* pos_w_eps = (const float*)d_in[11];
  const float* pos_b_mu = (const float*)d_in[12];
  const float* pos_b_rho = (const float*)d_in[13];
  const float* pos_b_eps = (const float*)d_in[14];
  const float* out_w_mu = (const float*)d_in[15];
  const float* out_w_rho = (const float*)d_in[16];
  const float* out_w_eps = (const float*)d_in[17];
  const float* out_b_mu = (const float*)d_in[18];
  const float* out_b_rho = (const float*)d_in[19];
  const float* out_b_eps = (const float*)d_in[20];
  const float* rw_mu = (const float*)d_in[21];
  const float* rw_rho = (const float*)d_in[22];
  const float* rw_eps = (const float*)d_in[23];
  const float* rr_mu = (const float*)d_in[24];
  const float* rr_rho = (const float*)d_in[25];
  const float* rr_eps = (const float*)d_in[26];

  char* ws = (char*)d_ws;
  ushort_t* in_w_bf  = (ushort_t*)(ws + 0);
  ushort_t* pos_w_bf = (ushort_t*)(ws + 6291456);
  ushort_t* out_w_bf = (ushort_t*)(ws + 8388608);
  float* in_b  = (float*)(ws + 10485760);
  float* pos_b = (float*)(ws + 10498048);
  float* out_b = (float*)(ws + 10502144);
  float* rwb   = (float*)(ws + 10506240);
  float* rrb   = (float*)(ws + 10510336);
  ushort_t* x_bf    = (ushort_t*)(ws + 10514432);
  ushort_t* posx_bf = (ushort_t*)(ws + 18903040);
  ushort_t* qrw = (ushort_t*)(ws + 21000192);
  ushort_t* qrr = (ushort_t*)(ws + 29388800);
  ushort_t* kb  = (ushort_t*)(ws + 37777408);
  ushort_t* vt  = (ushort_t*)(ws + 46166016);
  ushort_t* rhp = (ushort_t*)(ws + 54554624);
  ushort_t* ctx = (ushort_t*)(ws + 56913920);

  sample_w_kernel<<<5120, 256, 0, stream>>>(in_w_mu, in_w_rho, in_w_eps, in_w_bf,
                                            pos_w_mu, pos_w_rho, pos_w_eps, pos_w_bf,
                                            out_w_mu, out_w_rho, out_w_eps, out_w_bf);
  sample_bias_kernel<<<28, 256, 0, stream>>>(in_b_mu, in_b_rho, in_b_eps, in_b,
                                             pos_b_mu, pos_b_rho, pos_b_eps, pos_b,
                                             out_b_mu, out_b_rho, out_b_eps, out_b,
                                             rw_mu, rw_rho, rw_eps, rwb,
                                             rr_mu, rr_rho, rr_eps, rrb);
  cast_bf16x4_kernel<<<4096, 256, 0, stream>>>(x, x_bf, 1048576);
  cast_bf16x4_kernel<<<1024, 256, 0, stream>>>(pos, posx_bf, 262144);
  zero_rhp_pad_kernel<<<512, 256, 0, stream>>>(rhp);

  gemm_qkvpos_kernel<<<832, 256, 0, stream>>>(x_bf, in_w_bf, in_b, rwb, rrb,
                                              posx_bf, pos_w_bf, pos_b,
                                              qrw, qrr, kb, vt, rhp);

  attn_kernel<<<dim3(1024), 256, 0, stream>>>(qrw, qrr, kb, vt, rhp, ctx);

  gemm_bt_kernel<<<dim3(32, 8), 256, 0, stream>>>(ctx, out_w_bf, out_b, (float*)d_out, 4096, 1024, 1024);
}